// Round 19
// baseline (62.114 us; speedup 1.0000x reference)
//
#include <hip/hip_runtime.h>
#include <hip/hip_bf16.h>

constexpr int D_ = 8, H_ = 64, W_ = 64, C_ = 96;
constexpr int WC    = W_ * C_;            // 6144
constexpr int HWC   = H_ * W_ * C_;       // 393216
constexpr int BDHWC = 2 * D_ * HWC;       // 6291456 (elements per tensor)
constexpr float SCALE = 0.10206207261596577f;  // (384/4)^-0.5

typedef __attribute__((ext_vector_type(4))) float f32x4;
typedef __attribute__((ext_vector_type(8))) short s16x8;

__device__ inline ushort f2bf(float x) {
  union { __hip_bfloat16 h; ushort u; } c;
  c.h = __float2bfloat16(x);
  return c.u;
}
__device__ inline float bf2f(ushort u) {
  union { float f; unsigned i; } c;
  c.i = ((unsigned)u) << 16;
  return c.f;
}
__device__ inline int xswz8(int bid, int nwg) {
  return (bid & 7) * (nwg >> 3) + (bid >> 3);
}

// ================= Kernel A: MFMA attention, half-P, 37.4KB LDS =================
// (unchanged — ~20 us; attn rows bf16 -> ws[0..BDHWC), V bf16 -> ws[BDHWC..))
constexpr int QSTR  = 40;
constexpr int PSTR  = 136;
constexpr int PSTR2 = 72;

template <bool WSOUT>
__global__ void __launch_bounds__(256, 4)
attn_mfma_kernel(const float* __restrict__ qkv, float* __restrict__ out,
                 ushort* __restrict__ ws) {
  __shared__ ushort sK[128 * QSTR];    // 10240 B
  __shared__ ushort sVt[32 * PSTR];    //  8704 B
  __shared__ ushort sP[128 * PSTR2];   // 18432 B

  const int t    = threadIdx.x;
  const int bid  = xswz8(blockIdx.x, 2048);
  const int head = bid & 3;
  const int nw   = bid >> 2;
  const int wq   = nw & 31;
  const int d    = (nw >> 5) & 7;
  const int b    = nw >> 8;
  const int hc   = head * 24;

  const float* qpl = qkv + (size_t)(b * 8 + d) * HWC;
  const float* kpl = qpl + BDHWC;
  const float* vpl = kpl + BDHWC;
  ushort* wvpl = ws + BDHWC + (size_t)(b * 8 + d) * HWC;   // V bf16 out

  {
    const s16x8 Z = {0, 0, 0, 0, 0, 0, 0, 0};
    int row = t >> 1, col = 24 + (t & 1) * 8;
    *reinterpret_cast<s16x8*>(&sK[row * QSTR + col]) = Z;
    if (t < 136) *reinterpret_cast<s16x8*>(&sVt[24 * PSTR + t * 8]) = Z;
  }

  #pragma unroll
  for (int it = 0; it < 3; ++it) {
    int idx = t + it * 256;
    int tok = idx / 6, c4 = (idx - tok * 6) * 4;
    int g = (tok >> 1) * WC + (wq * 2 + (tok & 1)) * 96 + hc + c4;
    float4 kv = *reinterpret_cast<const float4*>(kpl + g);
    float4 vv = *reinterpret_cast<const float4*>(vpl + g);
    ushort4 kh = { f2bf(kv.x), f2bf(kv.y), f2bf(kv.z), f2bf(kv.w) };
    ushort4 vh = { f2bf(vv.x), f2bf(vv.y), f2bf(vv.z), f2bf(vv.w) };
    *reinterpret_cast<ushort4*>(&sK[tok * QSTR + c4]) = kh;
    sVt[(c4 + 0) * PSTR + tok] = vh.x;
    sVt[(c4 + 1) * PSTR + tok] = vh.y;
    sVt[(c4 + 2) * PSTR + tok] = vh.z;
    sVt[(c4 + 3) * PSTR + tok] = vh.w;
    if (WSOUT) *reinterpret_cast<ushort4*>(wvpl + g) = vh;   // V bf16 handoff
  }

  const int wv = t >> 6, lane = t & 63;
  const int lr = lane & 15;
  const int lg = lane >> 4;
  const int r0 = (2 * wv) * 16;
  const int r1 = (2 * wv + 1) * 16;

  s16x8 a0 = {0,0,0,0,0,0,0,0}, a1 = {0,0,0,0,0,0,0,0};
  if (lg < 3) {
    union { s16x8 v; ushort u[8]; } qa;
    int tok = r0 + lr;
    const float* qp = qpl + (tok >> 1) * WC + (wq * 2 + (tok & 1)) * 96 + hc + lg * 8;
    float4 x0 = *reinterpret_cast<const float4*>(qp);
    float4 x1 = *reinterpret_cast<const float4*>(qp + 4);
    qa.u[0] = f2bf(x0.x * SCALE); qa.u[1] = f2bf(x0.y * SCALE);
    qa.u[2] = f2bf(x0.z * SCALE); qa.u[3] = f2bf(x0.w * SCALE);
    qa.u[4] = f2bf(x1.x * SCALE); qa.u[5] = f2bf(x1.y * SCALE);
    qa.u[6] = f2bf(x1.z * SCALE); qa.u[7] = f2bf(x1.w * SCALE);
    a0 = qa.v;
    tok = r1 + lr;
    qp = qpl + (tok >> 1) * WC + (wq * 2 + (tok & 1)) * 96 + hc + lg * 8;
    x0 = *reinterpret_cast<const float4*>(qp);
    x1 = *reinterpret_cast<const float4*>(qp + 4);
    qa.u[0] = f2bf(x0.x * SCALE); qa.u[1] = f2bf(x0.y * SCALE);
    qa.u[2] = f2bf(x0.z * SCALE); qa.u[3] = f2bf(x0.w * SCALE);
    qa.u[4] = f2bf(x1.x * SCALE); qa.u[5] = f2bf(x1.y * SCALE);
    qa.u[6] = f2bf(x1.z * SCALE); qa.u[7] = f2bf(x1.w * SCALE);
    a1 = qa.v;
  }

  __syncthreads();

  float rsum[2][4];
  #pragma unroll
  for (int rb = 0; rb < 2; ++rb)
    #pragma unroll
    for (int r = 0; r < 4; ++r) rsum[rb][r] = 0.f;

  f32x4 accO[2][2];
  #pragma unroll
  for (int i = 0; i < 2; ++i)
    #pragma unroll
    for (int j = 0; j < 2; ++j) accO[i][j] = f32x4{0.f, 0.f, 0.f, 0.f};

  #pragma unroll
  for (int half = 0; half < 2; ++half) {
    f32x4 accS[2][4];
    #pragma unroll
    for (int i = 0; i < 2; ++i)
      #pragma unroll
      for (int j = 0; j < 4; ++j) accS[i][j] = f32x4{0.f, 0.f, 0.f, 0.f};

    #pragma unroll
    for (int nb = 0; nb < 4; ++nb) {
      s16x8 bb = *reinterpret_cast<const s16x8*>(
          &sK[(half * 64 + nb * 16 + lr) * QSTR + lg * 8]);
      accS[0][nb] = __builtin_amdgcn_mfma_f32_16x16x32_bf16(a0, bb, accS[0][nb], 0, 0, 0);
      accS[1][nb] = __builtin_amdgcn_mfma_f32_16x16x32_bf16(a1, bb, accS[1][nb], 0, 0, 0);
    }

    #pragma unroll
    for (int rb = 0; rb < 2; ++rb)
      #pragma unroll
      for (int nb = 0; nb < 4; ++nb)
        #pragma unroll
        for (int r = 0; r < 4; ++r) {
          float e = __expf(accS[rb][nb][r]);
          accS[rb][nb][r] = e;
          rsum[rb][r] += e;
        }

    if (half) __syncthreads();

    #pragma unroll
    for (int rb = 0; rb < 2; ++rb)
      #pragma unroll
      for (int nb = 0; nb < 4; ++nb)
        #pragma unroll
        for (int r = 0; r < 4; ++r)
          sP[((2 * wv + rb) * 16 + lg * 4 + r) * PSTR2 + nb * 16 + lr] =
              f2bf(accS[rb][nb][r]);
    __syncthreads();

    #pragma unroll
    for (int kb = 0; kb < 2; ++kb) {
      int kc = half * 64 + kb * 32 + lg * 8;
      s16x8 pa0 = *reinterpret_cast<const s16x8*>(&sP[(r0 + lr) * PSTR2 + kb * 32 + lg * 8]);
      s16x8 pa1 = *reinterpret_cast<const s16x8*>(&sP[(r1 + lr) * PSTR2 + kb * 32 + lg * 8]);
      s16x8 vb0 = *reinterpret_cast<const s16x8*>(&sVt[lr * PSTR + kc]);
      s16x8 vb1 = *reinterpret_cast<const s16x8*>(&sVt[(16 + lr) * PSTR + kc]);
      accO[0][0] = __builtin_amdgcn_mfma_f32_16x16x32_bf16(pa0, vb0, accO[0][0], 0, 0, 0);
      accO[0][1] = __builtin_amdgcn_mfma_f32_16x16x32_bf16(pa0, vb1, accO[0][1], 0, 0, 0);
      accO[1][0] = __builtin_amdgcn_mfma_f32_16x16x32_bf16(pa1, vb0, accO[1][0], 0, 0, 0);
      accO[1][1] = __builtin_amdgcn_mfma_f32_16x16x32_bf16(pa1, vb1, accO[1][1], 0, 0, 0);
    }
  }

  float* opl   = out + (size_t)(b * 8 + d) * HWC;
  ushort* wpl  = ws  + (size_t)(b * 8 + d) * HWC;
  #pragma unroll
  for (int rb = 0; rb < 2; ++rb) {
    #pragma unroll
    for (int r = 0; r < 4; ++r) {
      float s = rsum[rb][r];
      s += __shfl_xor(s, 1); s += __shfl_xor(s, 2);
      s += __shfl_xor(s, 4); s += __shfl_xor(s, 8);
      int tok = (2 * wv + rb) * 16 + lg * 4 + r;
      int g = (tok >> 1) * WC + (wq * 2 + (tok & 1)) * 96 + hc;
      float inv = 1.0f / s;
      if (WSOUT) {
        wpl[g + lr] = f2bf(accO[rb][0][r] * inv);
        if (lr < 8) wpl[g + 16 + lr] = f2bf(accO[rb][1][r] * inv);
      } else {
        opl[g + lr] = accO[rb][0][r] * inv;
        if (lr < 8) opl[g + 16 + lr] = accO[rb][1][r] * inv;
      }
    }
  }
}

// ====== Kernel CB: LePE + MFMA proj — 3-row staging per zd (6 barriers) ======
// Per dd phase: stage ALL 3 zh rows (or zeros) into sV[3][66][104], then 9
// factor-free taps. dd keeps the continue guard (hoist fence, r15-proven).
// LDS 67.1KB -> 2 blocks/CU; (256,2) -> 128-VGPR cap.
constexpr int VSTR = 104;
constexpr int WSTR = 104;

template <bool WSIN>
__global__ void __launch_bounds__(256, 2)
lepe_proj_fused_kernel(const float* __restrict__ qkv, const float* __restrict__ cw,
                       const float* __restrict__ cbias, const float* __restrict__ pw,
                       const float* __restrict__ pb, float* __restrict__ io,
                       const ushort* __restrict__ ws) {
  __shared__ ushort sV[3][66 * VSTR]; // 41184 B (w-halo rows 0,65 zero)
  __shared__ ushort sW[96 * WSTR];    // 19968 B
  __shared__ ushort sCW[27 * 96];     //  5184 B
  __shared__ float  sCB[96];
  __shared__ float  sPB[96];

  const int t   = threadIdx.x;
  const int bid = xswz8(blockIdx.x, 1024);
  const int h   = bid & 63;
  const int d   = (bid >> 6) & 7;
  const int b   = bid >> 9;

  float* iop = io + (size_t)(b * 8 + d) * HWC + h * WC;
  const ushort* wsp = ws + (size_t)(b * 8 + d) * HWC + h * WC;       // attn rows
  const ushort* wvb = ws + BDHWC + (size_t)b * 8 * HWC;              // V bf16 batch
  const float* vbatch = qkv + 2 * (size_t)BDHWC + (size_t)b * 8 * HWC;

  const int tt  = t >> 2;
  const int cbk = (t & 3) * 24;

  // ---- attn rows: issue reads first ----
  float lep[24];
  if (WSIN) {
    union { s16x8 v; ushort u[8]; } azu[3];
    #pragma unroll
    for (int k = 0; k < 3; ++k)
      azu[k].v = *reinterpret_cast<const s16x8*>(wsp + tt * 96 + cbk + k * 8);
    #pragma unroll
    for (int k = 0; k < 3; ++k)
      #pragma unroll
      for (int e = 0; e < 8; ++e) lep[8*k+e] = bf2f(azu[k].u[e]);
  } else {
    float4 az[6];
    #pragma unroll
    for (int j = 0; j < 6; ++j)
      az[j] = *reinterpret_cast<const float4*>(iop + tt * 96 + cbk + j * 4);
    #pragma unroll
    for (int j = 0; j < 6; ++j) {
      lep[4*j+0] = az[j].x; lep[4*j+1] = az[j].y;
      lep[4*j+2] = az[j].z; lep[4*j+3] = az[j].w;
    }
  }

  // ---- zero w-halo rows (rows 0 and 65 of each of 3 buffers), once ----
  if (t < 78) {
    const s16x8 Z = {0, 0, 0, 0, 0, 0, 0, 0};
    int buf = t / 26, rr = t - buf * 26;
    int row = (rr < 13) ? 0 : 65;
    int col = (rr < 13 ? rr : rr - 13) * 8;
    *reinterpret_cast<s16x8*>(&sV[buf][row * VSTR + col]) = Z;
  }

  // ---- stage weights ----
  #pragma unroll
  for (int it = 0; it < 9; ++it) {
    int idx = t + it * 256;
    int co = idx / 24, c4 = (idx - co * 24) * 4;
    float4 x = *reinterpret_cast<const float4*>(pw + co * 96 + c4);
    ushort4 hx = { f2bf(x.x), f2bf(x.y), f2bf(x.z), f2bf(x.w) };
    *reinterpret_cast<ushort4*>(&sW[co * WSTR + c4]) = hx;
  }
  for (int idx = t; idx < 2592; idx += 256) {
    int c = idx / 27, tap = idx - c * 27;
    sCW[tap * 96 + c] = f2bf(cw[idx]);
  }
  if (t < 96) { sCB[t] = cbias[t]; sPB[t] = pb[t]; }

  // factor-free taps (w-halo handles w edges; zero rows handle zh edges)
  #define TAP(BUF, row, tap)                                                 \
    {                                                                        \
      _Pragma("unroll")                                                      \
      for (int j8 = 0; j8 < 3; ++j8) {                                       \
        union { s16x8 v; ushort u[8]; } vu;                                  \
        vu.v = *reinterpret_cast<const s16x8*>(&sV[BUF][(row) * VSTR + cbk + j8 * 8]); \
        union { s16x8 v; ushort u[8]; } wu;                                  \
        wu.v = *reinterpret_cast<const s16x8*>(&sCW[(tap) * 96 + cbk + j8 * 8]); \
        _Pragma("unroll")                                                    \
        for (int e = 0; e < 8; ++e)                                          \
          lep[8*j8+e] = fmaf(bf2f(vu.u[e]), bf2f(wu.u[e]), lep[8*j8+e]);     \
      }                                                                      \
    }

  #pragma unroll
  for (int dd = 0; dd < 3; ++dd) {
    int zd = d + dd - 1;
    if (zd < 0 || zd >= D_) continue;        // block-uniform hoist fence
    __syncthreads();   // previous phase's taps done reading sV

    // stage 3 zh rows (or zeros) into sV[0..2], rows 1..64
    #pragma unroll
    for (int dh = 0; dh < 3; ++dh) {
      int zh = h + dh - 1;
      if (zh >= 0 && zh < H_) {              // block-uniform
        if (WSIN) {
          const ushort* vrow = wvb + (size_t)zd * HWC + zh * WC;
          #pragma unroll
          for (int it = 0; it < 3; ++it) {
            int idx = t + it * 256;
            int tok = idx / 12, c8 = idx - tok * 12;
            s16x8 x = *reinterpret_cast<const s16x8*>(vrow + tok * 96 + c8 * 8);
            *reinterpret_cast<s16x8*>(&sV[dh][(tok + 1) * VSTR + c8 * 8]) = x;
          }
        } else {
          const float4* src = reinterpret_cast<const float4*>(
              vbatch + (size_t)zd * HWC + zh * WC);
          #pragma unroll
          for (int it = 0; it < 6; ++it) {
            int idx = t + it * 256;
            int tok = idx / 24, c4 = idx - tok * 24;
            float4 x = src[idx];
            ushort4 hx = { f2bf(x.x), f2bf(x.y), f2bf(x.z), f2bf(x.w) };
            *reinterpret_cast<ushort4*>(&sV[dh][(tok + 1) * VSTR + c4 * 4]) = hx;
          }
        }
      } else {
        const s16x8 Z = {0, 0, 0, 0, 0, 0, 0, 0};
        #pragma unroll
        for (int it = 0; it < 3; ++it) {
          int idx = t + it * 256;
          int tok = idx / 12, c8 = idx - tok * 12;
          *reinterpret_cast<s16x8*>(&sV[dh][(tok + 1) * VSTR + c8 * 8]) = Z;
        }
      }
    }
    __syncthreads();   // all 3 rows ready

    const int tap0 = dd * 9;
    #pragma unroll
    for (int dh = 0; dh < 3; ++dh) {
      TAP(dh, tt,     tap0 + dh * 3 + 0);
      TAP(dh, tt + 1, tap0 + dh * 3 + 1);
      TAP(dh, tt + 2, tap0 + dh * 3 + 2);
    }
  }
  #undef TAP

  // ---- buffers dead: repack (lep + conv bias) bf16 into sV[0] rows 0..63 ----
  __syncthreads();
  #pragma unroll
  for (int j = 0; j < 6; ++j) {
    float4 bz = *reinterpret_cast<const float4*>(sCB + cbk + j * 4);
    ushort4 hx = { f2bf(lep[4*j+0] + bz.x), f2bf(lep[4*j+1] + bz.y),
                   f2bf(lep[4*j+2] + bz.z), f2bf(lep[4*j+3] + bz.w) };
    *reinterpret_cast<ushort4*>(&sV[0][tt * VSTR + cbk + j * 4]) = hx;
  }
  __syncthreads();

  const int wv = t >> 6, lane = t & 63;
  const int lr = lane & 15, lg = lane >> 4;

  f32x4 acc[6];
  #pragma unroll
  for (int cb = 0; cb < 6; ++cb) {
    float bv = sPB[cb * 16 + lr];
    acc[cb] = f32x4{bv, bv, bv, bv};
  }
  s16x8 afr[3];
  #pragma unroll
  for (int kb = 0; kb < 3; ++kb)
    afr[kb] = *reinterpret_cast<const s16x8*>(&sV[0][(wv * 16 + lr) * VSTR + kb * 32 + lg * 8]);
  #pragma unroll
  for (int kb = 0; kb < 3; ++kb) {
    #pragma unroll
    for (int cb = 0; cb < 6; ++cb) {
      s16x8 bfr = *reinterpret_cast<const s16x8*>(&sW[(cb * 16 + lr) * WSTR + kb * 32 + lg * 8]);
      acc[cb] = __builtin_amdgcn_mfma_f32_16x16x32_bf16(afr[kb], bfr, acc[cb], 0, 0, 0);
    }
  }

  #pragma unroll
  for (int cb = 0; cb < 6; ++cb) {
    #pragma unroll
    for (int r = 0; r < 4; ++r) {
      int tok = wv * 16 + lg * 4 + r;
      iop[tok * 96 + cb * 16 + lr] = acc[cb][r];
    }
  }
}

extern "C" void kernel_launch(void* const* d_in, const int* in_sizes, int n_in,
                              void* d_out, int out_size, void* d_ws, size_t ws_size,
                              hipStream_t stream) {
  const float* qkv = (const float*)d_in[0];
  const float* cw  = (const float*)d_in[1];
  const float* cb  = (const float*)d_in[2];
  const float* pw  = (const float*)d_in[3];
  const float* pb  = (const float*)d_in[4];
  float* out = (float*)d_out;
  ushort* ws = (ushort*)d_ws;

  const size_t need = (size_t)2 * BDHWC * sizeof(ushort);  // 25.2 MB
  if (ws_size >= need) {
    hipLaunchKernelGGL((attn_mfma_kernel<true>), dim3(2048), dim3(256), 0, stream,
                       qkv, out, ws);
    hipLaunchKernelGGL((lepe_proj_fused_kernel<true>), dim3(1024), dim3(256), 0, stream,
                       qkv, cw, cb, pw, pb, out, ws);
  } else {
    hipLaunchKernelGGL((attn_mfma_kernel<false>), dim3(2048), dim3(256), 0, stream,
                       qkv, out, ws);
    hipLaunchKernelGGL((lepe_proj_fused_kernel<false>), dim3(1024), dim3(256), 0, stream,
                       qkv, cw, cb, pw, pb, out, ws);
  }
}

// Round 20
// 56.699 us; speedup vs baseline: 1.0955x; 1.0955x over previous
//
#include <hip/hip_runtime.h>
#include <hip/hip_bf16.h>

constexpr int D_ = 8, H_ = 64, W_ = 64, C_ = 96;
constexpr int WC    = W_ * C_;            // 6144
constexpr int HWC   = H_ * W_ * C_;       // 393216
constexpr int BDHWC = 2 * D_ * HWC;       // 6291456 (elements per tensor)
constexpr float SCALE = 0.10206207261596577f;  // (384/4)^-0.5

typedef __attribute__((ext_vector_type(4))) float f32x4;
typedef __attribute__((ext_vector_type(8))) short s16x8;

__device__ inline ushort f2bf(float x) {
  union { __hip_bfloat16 h; ushort u; } c;
  c.h = __float2bfloat16(x);
  return c.u;
}
__device__ inline float bf2f(ushort u) {
  union { float f; unsigned i; } c;
  c.i = ((unsigned)u) << 16;
  return c.f;
}
__device__ inline int xswz8(int bid, int nwg) {
  return (bid & 7) * (nwg >> 3) + (bid >> 3);
}

// ================= Kernel A: MFMA attention, half-P, 37.4KB LDS =================
// WSOUT=1: attn rows bf16 -> ws[0..BDHWC); V bf16 -> ws[BDHWC..2*BDHWC).
constexpr int QSTR  = 40;
constexpr int PSTR  = 136;
constexpr int PSTR2 = 72;

template <bool WSOUT>
__global__ void __launch_bounds__(256, 4)
attn_mfma_kernel(const float* __restrict__ qkv, float* __restrict__ out,
                 ushort* __restrict__ ws) {
  __shared__ ushort sK[128 * QSTR];    // 10240 B
  __shared__ ushort sVt[32 * PSTR];    //  8704 B
  __shared__ ushort sP[128 * PSTR2];   // 18432 B

  const int t    = threadIdx.x;
  const int bid  = xswz8(blockIdx.x, 2048);
  const int head = bid & 3;
  const int nw   = bid >> 2;
  const int wq   = nw & 31;
  const int d    = (nw >> 5) & 7;
  const int b    = nw >> 8;
  const int hc   = head * 24;

  const float* qpl = qkv + (size_t)(b * 8 + d) * HWC;
  const float* kpl = qpl + BDHWC;
  const float* vpl = kpl + BDHWC;
  ushort* wvpl = ws + BDHWC + (size_t)(b * 8 + d) * HWC;   // V bf16 out

  {
    const s16x8 Z = {0, 0, 0, 0, 0, 0, 0, 0};
    int row = t >> 1, col = 24 + (t & 1) * 8;
    *reinterpret_cast<s16x8*>(&sK[row * QSTR + col]) = Z;
    if (t < 136) *reinterpret_cast<s16x8*>(&sVt[24 * PSTR + t * 8]) = Z;
  }

  #pragma unroll
  for (int it = 0; it < 3; ++it) {
    int idx = t + it * 256;
    int tok = idx / 6, c4 = (idx - tok * 6) * 4;
    int g = (tok >> 1) * WC + (wq * 2 + (tok & 1)) * 96 + hc + c4;
    float4 kv = *reinterpret_cast<const float4*>(kpl + g);
    float4 vv = *reinterpret_cast<const float4*>(vpl + g);
    ushort4 kh = { f2bf(kv.x), f2bf(kv.y), f2bf(kv.z), f2bf(kv.w) };
    ushort4 vh = { f2bf(vv.x), f2bf(vv.y), f2bf(vv.z), f2bf(vv.w) };
    *reinterpret_cast<ushort4*>(&sK[tok * QSTR + c4]) = kh;
    sVt[(c4 + 0) * PSTR + tok] = vh.x;
    sVt[(c4 + 1) * PSTR + tok] = vh.y;
    sVt[(c4 + 2) * PSTR + tok] = vh.z;
    sVt[(c4 + 3) * PSTR + tok] = vh.w;
    if (WSOUT) *reinterpret_cast<ushort4*>(wvpl + g) = vh;   // V bf16 handoff
  }

  const int wv = t >> 6, lane = t & 63;
  const int lr = lane & 15;
  const int lg = lane >> 4;
  const int r0 = (2 * wv) * 16;
  const int r1 = (2 * wv + 1) * 16;

  s16x8 a0 = {0,0,0,0,0,0,0,0}, a1 = {0,0,0,0,0,0,0,0};
  if (lg < 3) {
    union { s16x8 v; ushort u[8]; } qa;
    int tok = r0 + lr;
    const float* qp = qpl + (tok >> 1) * WC + (wq * 2 + (tok & 1)) * 96 + hc + lg * 8;
    float4 x0 = *reinterpret_cast<const float4*>(qp);
    float4 x1 = *reinterpret_cast<const float4*>(qp + 4);
    qa.u[0] = f2bf(x0.x * SCALE); qa.u[1] = f2bf(x0.y * SCALE);
    qa.u[2] = f2bf(x0.z * SCALE); qa.u[3] = f2bf(x0.w * SCALE);
    qa.u[4] = f2bf(x1.x * SCALE); qa.u[5] = f2bf(x1.y * SCALE);
    qa.u[6] = f2bf(x1.z * SCALE); qa.u[7] = f2bf(x1.w * SCALE);
    a0 = qa.v;
    tok = r1 + lr;
    qp = qpl + (tok >> 1) * WC + (wq * 2 + (tok & 1)) * 96 + hc + lg * 8;
    x0 = *reinterpret_cast<const float4*>(qp);
    x1 = *reinterpret_cast<const float4*>(qp + 4);
    qa.u[0] = f2bf(x0.x * SCALE); qa.u[1] = f2bf(x0.y * SCALE);
    qa.u[2] = f2bf(x0.z * SCALE); qa.u[3] = f2bf(x0.w * SCALE);
    qa.u[4] = f2bf(x1.x * SCALE); qa.u[5] = f2bf(x1.y * SCALE);
    qa.u[6] = f2bf(x1.z * SCALE); qa.u[7] = f2bf(x1.w * SCALE);
    a1 = qa.v;
  }

  __syncthreads();

  float rsum[2][4];
  #pragma unroll
  for (int rb = 0; rb < 2; ++rb)
    #pragma unroll
    for (int r = 0; r < 4; ++r) rsum[rb][r] = 0.f;

  f32x4 accO[2][2];
  #pragma unroll
  for (int i = 0; i < 2; ++i)
    #pragma unroll
    for (int j = 0; j < 2; ++j) accO[i][j] = f32x4{0.f, 0.f, 0.f, 0.f};

  #pragma unroll
  for (int half = 0; half < 2; ++half) {
    f32x4 accS[2][4];
    #pragma unroll
    for (int i = 0; i < 2; ++i)
      #pragma unroll
      for (int j = 0; j < 4; ++j) accS[i][j] = f32x4{0.f, 0.f, 0.f, 0.f};

    #pragma unroll
    for (int nb = 0; nb < 4; ++nb) {
      s16x8 bb = *reinterpret_cast<const s16x8*>(
          &sK[(half * 64 + nb * 16 + lr) * QSTR + lg * 8]);
      accS[0][nb] = __builtin_amdgcn_mfma_f32_16x16x32_bf16(a0, bb, accS[0][nb], 0, 0, 0);
      accS[1][nb] = __builtin_amdgcn_mfma_f32_16x16x32_bf16(a1, bb, accS[1][nb], 0, 0, 0);
    }

    #pragma unroll
    for (int rb = 0; rb < 2; ++rb)
      #pragma unroll
      for (int nb = 0; nb < 4; ++nb)
        #pragma unroll
        for (int r = 0; r < 4; ++r) {
          float e = __expf(accS[rb][nb][r]);
          accS[rb][nb][r] = e;
          rsum[rb][r] += e;
        }

    if (half) __syncthreads();

    #pragma unroll
    for (int rb = 0; rb < 2; ++rb)
      #pragma unroll
      for (int nb = 0; nb < 4; ++nb)
        #pragma unroll
        for (int r = 0; r < 4; ++r)
          sP[((2 * wv + rb) * 16 + lg * 4 + r) * PSTR2 + nb * 16 + lr] =
              f2bf(accS[rb][nb][r]);
    __syncthreads();

    #pragma unroll
    for (int kb = 0; kb < 2; ++kb) {
      int kc = half * 64 + kb * 32 + lg * 8;
      s16x8 pa0 = *reinterpret_cast<const s16x8*>(&sP[(r0 + lr) * PSTR2 + kb * 32 + lg * 8]);
      s16x8 pa1 = *reinterpret_cast<const s16x8*>(&sP[(r1 + lr) * PSTR2 + kb * 32 + lg * 8]);
      s16x8 vb0 = *reinterpret_cast<const s16x8*>(&sVt[lr * PSTR + kc]);
      s16x8 vb1 = *reinterpret_cast<const s16x8*>(&sVt[(16 + lr) * PSTR + kc]);
      accO[0][0] = __builtin_amdgcn_mfma_f32_16x16x32_bf16(pa0, vb0, accO[0][0], 0, 0, 0);
      accO[0][1] = __builtin_amdgcn_mfma_f32_16x16x32_bf16(pa0, vb1, accO[0][1], 0, 0, 0);
      accO[1][0] = __builtin_amdgcn_mfma_f32_16x16x32_bf16(pa1, vb0, accO[1][0], 0, 0, 0);
      accO[1][1] = __builtin_amdgcn_mfma_f32_16x16x32_bf16(pa1, vb1, accO[1][1], 0, 0, 0);
    }
  }

  float* opl   = out + (size_t)(b * 8 + d) * HWC;
  ushort* wpl  = ws  + (size_t)(b * 8 + d) * HWC;
  #pragma unroll
  for (int rb = 0; rb < 2; ++rb) {
    #pragma unroll
    for (int r = 0; r < 4; ++r) {
      float s = rsum[rb][r];
      s += __shfl_xor(s, 1); s += __shfl_xor(s, 2);
      s += __shfl_xor(s, 4); s += __shfl_xor(s, 8);
      int tok = (2 * wv + rb) * 16 + lg * 4 + r;
      int g = (tok >> 1) * WC + (wq * 2 + (tok & 1)) * 96 + hc;
      float inv = 1.0f / s;
      if (WSOUT) {
        wpl[g + lr] = f2bf(accO[rb][0][r] * inv);
        if (lr < 8) wpl[g + 16 + lr] = f2bf(accO[rb][1][r] * inv);
      } else {
        opl[g + lr] = accO[rb][0][r] * inv;
        if (lr < 8) opl[g + 16 + lr] = accO[rb][1][r] * inv;
      }
    }
  }
}

// ====== Kernel CB: fused LePE + MFMA proj — r15 CFG + zero-halo V rows ======
// sV has 66 rows: row 0 and row 65 are permanent zeros (conv zero-pad).
// Staging writes V[w] -> sV[w+1]; taps read rows tt, tt+1, tt+2 with NO
// per-lane clamp/factor ops. CFG identical to r15 (continue-guarded regions).
constexpr int VSTR = 104;
constexpr int WSTR = 104;

template <bool WSIN>
__global__ void __launch_bounds__(256, 4)
lepe_proj_fused_kernel(const float* __restrict__ qkv, const float* __restrict__ cw,
                       const float* __restrict__ cbias, const float* __restrict__ pw,
                       const float* __restrict__ pb, float* __restrict__ io,
                       const ushort* __restrict__ ws) {
  __shared__ ushort sV[66 * VSTR];    // 13728 B (rows 0,65 = zero halo)
  __shared__ ushort sW[96 * WSTR];    // 19968 B
  __shared__ ushort sCW[27 * 96];     //  5184 B
  __shared__ float  sCB[96];
  __shared__ float  sPB[96];

  const int t   = threadIdx.x;
  const int bid = xswz8(blockIdx.x, 1024);
  const int h   = bid & 63;
  const int d   = (bid >> 6) & 7;
  const int b   = bid >> 9;

  float* iop = io + (size_t)(b * 8 + d) * HWC + h * WC;
  const ushort* wsp = ws + (size_t)(b * 8 + d) * HWC + h * WC;       // attn rows
  const ushort* wvb = ws + BDHWC + (size_t)b * 8 * HWC;              // V bf16 batch
  const float* vbatch = qkv + 2 * (size_t)BDHWC + (size_t)b * 8 * HWC;

  const int tt  = t >> 2;
  const int cbk = (t & 3) * 24;

  // ---- attn rows: issue reads first (in flight under weight staging) ----
  float lep[24];
  if (WSIN) {
    union { s16x8 v; ushort u[8]; } azu[3];
    #pragma unroll
    for (int k = 0; k < 3; ++k)
      azu[k].v = *reinterpret_cast<const s16x8*>(wsp + tt * 96 + cbk + k * 8);
    #pragma unroll
    for (int k = 0; k < 3; ++k)
      #pragma unroll
      for (int e = 0; e < 8; ++e) lep[8*k+e] = bf2f(azu[k].u[e]);
  } else {
    float4 az[6];
    #pragma unroll
    for (int j = 0; j < 6; ++j)
      az[j] = *reinterpret_cast<const float4*>(iop + tt * 96 + cbk + j * 4);
    #pragma unroll
    for (int j = 0; j < 6; ++j) {
      lep[4*j+0] = az[j].x; lep[4*j+1] = az[j].y;
      lep[4*j+2] = az[j].z; lep[4*j+3] = az[j].w;
    }
  }

  // ---- zero halo rows (once; visible after first region barrier) ----
  if (t < 26) {
    const s16x8 Z = {0, 0, 0, 0, 0, 0, 0, 0};
    int row = (t < 13) ? 0 : 65;
    int col = (t < 13 ? t : t - 13) * 8;
    *reinterpret_cast<s16x8*>(&sV[row * VSTR + col]) = Z;
  }

  // ---- stage weights ----
  #pragma unroll
  for (int it = 0; it < 9; ++it) {
    int idx = t + it * 256;
    int co = idx / 24, c4 = (idx - co * 24) * 4;
    float4 x = *reinterpret_cast<const float4*>(pw + co * 96 + c4);
    ushort4 hx = { f2bf(x.x), f2bf(x.y), f2bf(x.z), f2bf(x.w) };
    *reinterpret_cast<ushort4*>(&sW[co * WSTR + c4]) = hx;
  }
  for (int idx = t; idx < 2592; idx += 256) {
    int c = idx / 27, tap = idx - c * 27;
    sCW[tap * 96 + c] = f2bf(cw[idx]);
  }
  if (t < 96) { sCB[t] = cbias[t]; sPB[t] = pb[t]; }

  // halo-indexed taps: rows tt (left), tt+1 (center), tt+2 (right); no factors
  #define TAP(row, tap)                                                      \
    {                                                                        \
      _Pragma("unroll")                                                      \
      for (int j8 = 0; j8 < 3; ++j8) {                                       \
        union { s16x8 v; ushort u[8]; } vu;                                  \
        vu.v = *reinterpret_cast<const s16x8*>(&sV[(row) * VSTR + cbk + j8 * 8]); \
        union { s16x8 v; ushort u[8]; } wu;                                  \
        wu.v = *reinterpret_cast<const s16x8*>(&sCW[(tap) * 96 + cbk + j8 * 8]); \
        _Pragma("unroll")                                                    \
        for (int e = 0; e < 8; ++e)                                          \
          lep[8*j8+e] = fmaf(bf2f(vu.u[e]), bf2f(wu.u[e]), lep[8*j8+e]);     \
      }                                                                      \
    }

  #pragma unroll
  for (int dd = 0; dd < 3; ++dd) {
    int zd = d + dd - 1;
    if (zd < 0 || zd >= D_) continue;        // block-uniform
    #pragma unroll
    for (int dh = 0; dh < 3; ++dh) {
      int zh = h + dh - 1;
      if (zh < 0 || zh >= H_) continue;      // block-uniform
      __syncthreads();   // previous sV fully consumed
      if (WSIN) {
        // pure bf16 copy into rows 1..64: 768 u16x8 chunks
        const ushort* vrow = wvb + (size_t)zd * HWC + zh * WC;
        #pragma unroll
        for (int it = 0; it < 3; ++it) {
          int idx = t + it * 256;
          int tok = idx / 12, c8 = idx - tok * 12;
          s16x8 x = *reinterpret_cast<const s16x8*>(vrow + tok * 96 + c8 * 8);
          *reinterpret_cast<s16x8*>(&sV[(tok + 1) * VSTR + c8 * 8]) = x;
        }
      } else {
        const float4* src = reinterpret_cast<const float4*>(
            vbatch + (size_t)zd * HWC + zh * WC);
        #pragma unroll
        for (int it = 0; it < 6; ++it) {
          int idx = t + it * 256;
          int tok = idx / 24, c4 = idx - tok * 24;
          float4 x = src[idx];
          ushort4 hx = { f2bf(x.x), f2bf(x.y), f2bf(x.z), f2bf(x.w) };
          *reinterpret_cast<ushort4*>(&sV[(tok + 1) * VSTR + c4 * 4]) = hx;
        }
      }
      __syncthreads();
      const int tap0 = dd * 9 + dh * 3;
      TAP(tt,     tap0 + 0);
      TAP(tt + 1, tap0 + 1);
      TAP(tt + 2, tap0 + 2);
    }
  }
  #undef TAP

  // ---- sV dead: repack (lep + conv bias) bf16 as proj input (rows 0..63) ----
  __syncthreads();
  #pragma unroll
  for (int j = 0; j < 6; ++j) {
    float4 bz = *reinterpret_cast<const float4*>(sCB + cbk + j * 4);
    ushort4 hx = { f2bf(lep[4*j+0] + bz.x), f2bf(lep[4*j+1] + bz.y),
                   f2bf(lep[4*j+2] + bz.z), f2bf(lep[4*j+3] + bz.w) };
    *reinterpret_cast<ushort4*>(&sV[tt * VSTR + cbk + j * 4]) = hx;
  }
  __syncthreads();

  const int wv = t >> 6, lane = t & 63;
  const int lr = lane & 15, lg = lane >> 4;

  f32x4 acc[6];
  #pragma unroll
  for (int cb = 0; cb < 6; ++cb) {
    float bv = sPB[cb * 16 + lr];
    acc[cb] = f32x4{bv, bv, bv, bv};
  }
  s16x8 afr[3];
  #pragma unroll
  for (int kb = 0; kb < 3; ++kb)
    afr[kb] = *reinterpret_cast<const s16x8*>(&sV[(wv * 16 + lr) * VSTR + kb * 32 + lg * 8]);
  #pragma unroll
  for (int kb = 0; kb < 3; ++kb) {
    #pragma unroll
    for (int cb = 0; cb < 6; ++cb) {
      s16x8 bfr = *reinterpret_cast<const s16x8*>(&sW[(cb * 16 + lr) * WSTR + kb * 32 + lg * 8]);
      acc[cb] = __builtin_amdgcn_mfma_f32_16x16x32_bf16(afr[kb], bfr, acc[cb], 0, 0, 0);
    }
  }

  #pragma unroll
  for (int cb = 0; cb < 6; ++cb) {
    #pragma unroll
    for (int r = 0; r < 4; ++r) {
      int tok = wv * 16 + lg * 4 + r;
      iop[tok * 96 + cb * 16 + lr] = acc[cb][r];
    }
  }
}

extern "C" void kernel_launch(void* const* d_in, const int* in_sizes, int n_in,
                              void* d_out, int out_size, void* d_ws, size_t ws_size,
                              hipStream_t stream) {
  const float* qkv = (const float*)d_in[0];
  const float* cw  = (const float*)d_in[1];
  const float* cb  = (const float*)d_in[2];
  const float* pw  = (const float*)d_in[3];
  const float* pb  = (const float*)d_in[4];
  float* out = (float*)d_out;
  ushort* ws = (ushort*)d_ws;

  const size_t need = (size_t)2 * BDHWC * sizeof(ushort);  // 25.2 MB
  if (ws_size >= need) {
    hipLaunchKernelGGL((attn_mfma_kernel<true>), dim3(2048), dim3(256), 0, stream,
                       qkv, out, ws);
    hipLaunchKernelGGL((lepe_proj_fused_kernel<true>), dim3(1024), dim3(256), 0, stream,
                       qkv, cw, cb, pw, pb, out, ws);
  } else {
    hipLaunchKernelGGL((attn_mfma_kernel<false>), dim3(2048), dim3(256), 0, stream,
                       qkv, out, ws);
    hipLaunchKernelGGL((lepe_proj_fused_kernel<false>), dim3(1024), dim3(256), 0, stream,
                       qkv, cw, cb, pw, pb, out, ws);
  }
}

// Round 21
// 56.063 us; speedup vs baseline: 1.1079x; 1.0113x over previous
//
#include <hip/hip_runtime.h>
#include <hip/hip_bf16.h>

constexpr int D_ = 8, H_ = 64, W_ = 64, C_ = 96;
constexpr int WC    = W_ * C_;            // 6144
constexpr int HWC   = H_ * W_ * C_;       // 393216
constexpr int BDHWC = 2 * D_ * HWC;       // 6291456 (elements per tensor)
constexpr float SCALE = 0.10206207261596577f;  // (384/4)^-0.5

typedef __attribute__((ext_vector_type(4))) float f32x4;
typedef __attribute__((ext_vector_type(8))) short s16x8;

__device__ inline ushort f2bf(float x) {
  union { __hip_bfloat16 h; ushort u; } c;
  c.h = __float2bfloat16(x);
  return c.u;
}
__device__ inline float bf2f(ushort u) {
  union { float f; unsigned i; } c;
  c.i = ((unsigned)u) << 16;
  return c.f;
}
__device__ inline int xswz8(int bid, int nwg) {
  return (bid & 7) * (nwg >> 3) + (bid >> 3);
}

// ================= Kernel A: MFMA attention, half-P, 37.4KB LDS =================
// (unchanged — ~20 us; attn rows bf16 -> ws[0..BDHWC), V bf16 -> ws[BDHWC..))
constexpr int QSTR  = 40;
constexpr int PSTR  = 136;
constexpr int PSTR2 = 72;

template <bool WSOUT>
__global__ void __launch_bounds__(256, 4)
attn_mfma_kernel(const float* __restrict__ qkv, float* __restrict__ out,
                 ushort* __restrict__ ws) {
  __shared__ ushort sK[128 * QSTR];    // 10240 B
  __shared__ ushort sVt[32 * PSTR];    //  8704 B
  __shared__ ushort sP[128 * PSTR2];   // 18432 B

  const int t    = threadIdx.x;
  const int bid  = xswz8(blockIdx.x, 2048);
  const int head = bid & 3;
  const int nw   = bid >> 2;
  const int wq   = nw & 31;
  const int d    = (nw >> 5) & 7;
  const int b    = nw >> 8;
  const int hc   = head * 24;

  const float* qpl = qkv + (size_t)(b * 8 + d) * HWC;
  const float* kpl = qpl + BDHWC;
  const float* vpl = kpl + BDHWC;
  ushort* wvpl = ws + BDHWC + (size_t)(b * 8 + d) * HWC;   // V bf16 out

  {
    const s16x8 Z = {0, 0, 0, 0, 0, 0, 0, 0};
    int row = t >> 1, col = 24 + (t & 1) * 8;
    *reinterpret_cast<s16x8*>(&sK[row * QSTR + col]) = Z;
    if (t < 136) *reinterpret_cast<s16x8*>(&sVt[24 * PSTR + t * 8]) = Z;
  }

  #pragma unroll
  for (int it = 0; it < 3; ++it) {
    int idx = t + it * 256;
    int tok = idx / 6, c4 = (idx - tok * 6) * 4;
    int g = (tok >> 1) * WC + (wq * 2 + (tok & 1)) * 96 + hc + c4;
    float4 kv = *reinterpret_cast<const float4*>(kpl + g);
    float4 vv = *reinterpret_cast<const float4*>(vpl + g);
    ushort4 kh = { f2bf(kv.x), f2bf(kv.y), f2bf(kv.z), f2bf(kv.w) };
    ushort4 vh = { f2bf(vv.x), f2bf(vv.y), f2bf(vv.z), f2bf(vv.w) };
    *reinterpret_cast<ushort4*>(&sK[tok * QSTR + c4]) = kh;
    sVt[(c4 + 0) * PSTR + tok] = vh.x;
    sVt[(c4 + 1) * PSTR + tok] = vh.y;
    sVt[(c4 + 2) * PSTR + tok] = vh.z;
    sVt[(c4 + 3) * PSTR + tok] = vh.w;
    if (WSOUT) *reinterpret_cast<ushort4*>(wvpl + g) = vh;   // V bf16 handoff
  }

  const int wv = t >> 6, lane = t & 63;
  const int lr = lane & 15;
  const int lg = lane >> 4;
  const int r0 = (2 * wv) * 16;
  const int r1 = (2 * wv + 1) * 16;

  s16x8 a0 = {0,0,0,0,0,0,0,0}, a1 = {0,0,0,0,0,0,0,0};
  if (lg < 3) {
    union { s16x8 v; ushort u[8]; } qa;
    int tok = r0 + lr;
    const float* qp = qpl + (tok >> 1) * WC + (wq * 2 + (tok & 1)) * 96 + hc + lg * 8;
    float4 x0 = *reinterpret_cast<const float4*>(qp);
    float4 x1 = *reinterpret_cast<const float4*>(qp + 4);
    qa.u[0] = f2bf(x0.x * SCALE); qa.u[1] = f2bf(x0.y * SCALE);
    qa.u[2] = f2bf(x0.z * SCALE); qa.u[3] = f2bf(x0.w * SCALE);
    qa.u[4] = f2bf(x1.x * SCALE); qa.u[5] = f2bf(x1.y * SCALE);
    qa.u[6] = f2bf(x1.z * SCALE); qa.u[7] = f2bf(x1.w * SCALE);
    a0 = qa.v;
    tok = r1 + lr;
    qp = qpl + (tok >> 1) * WC + (wq * 2 + (tok & 1)) * 96 + hc + lg * 8;
    x0 = *reinterpret_cast<const float4*>(qp);
    x1 = *reinterpret_cast<const float4*>(qp + 4);
    qa.u[0] = f2bf(x0.x * SCALE); qa.u[1] = f2bf(x0.y * SCALE);
    qa.u[2] = f2bf(x0.z * SCALE); qa.u[3] = f2bf(x0.w * SCALE);
    qa.u[4] = f2bf(x1.x * SCALE); qa.u[5] = f2bf(x1.y * SCALE);
    qa.u[6] = f2bf(x1.z * SCALE); qa.u[7] = f2bf(x1.w * SCALE);
    a1 = qa.v;
  }

  __syncthreads();

  float rsum[2][4];
  #pragma unroll
  for (int rb = 0; rb < 2; ++rb)
    #pragma unroll
    for (int r = 0; r < 4; ++r) rsum[rb][r] = 0.f;

  f32x4 accO[2][2];
  #pragma unroll
  for (int i = 0; i < 2; ++i)
    #pragma unroll
    for (int j = 0; j < 2; ++j) accO[i][j] = f32x4{0.f, 0.f, 0.f, 0.f};

  #pragma unroll
  for (int half = 0; half < 2; ++half) {
    f32x4 accS[2][4];
    #pragma unroll
    for (int i = 0; i < 2; ++i)
      #pragma unroll
      for (int j = 0; j < 4; ++j) accS[i][j] = f32x4{0.f, 0.f, 0.f, 0.f};

    #pragma unroll
    for (int nb = 0; nb < 4; ++nb) {
      s16x8 bb = *reinterpret_cast<const s16x8*>(
          &sK[(half * 64 + nb * 16 + lr) * QSTR + lg * 8]);
      accS[0][nb] = __builtin_amdgcn_mfma_f32_16x16x32_bf16(a0, bb, accS[0][nb], 0, 0, 0);
      accS[1][nb] = __builtin_amdgcn_mfma_f32_16x16x32_bf16(a1, bb, accS[1][nb], 0, 0, 0);
    }

    #pragma unroll
    for (int rb = 0; rb < 2; ++rb)
      #pragma unroll
      for (int nb = 0; nb < 4; ++nb)
        #pragma unroll
        for (int r = 0; r < 4; ++r) {
          float e = __expf(accS[rb][nb][r]);
          accS[rb][nb][r] = e;
          rsum[rb][r] += e;
        }

    if (half) __syncthreads();

    #pragma unroll
    for (int rb = 0; rb < 2; ++rb)
      #pragma unroll
      for (int nb = 0; nb < 4; ++nb)
        #pragma unroll
        for (int r = 0; r < 4; ++r)
          sP[((2 * wv + rb) * 16 + lg * 4 + r) * PSTR2 + nb * 16 + lr] =
              f2bf(accS[rb][nb][r]);
    __syncthreads();

    #pragma unroll
    for (int kb = 0; kb < 2; ++kb) {
      int kc = half * 64 + kb * 32 + lg * 8;
      s16x8 pa0 = *reinterpret_cast<const s16x8*>(&sP[(r0 + lr) * PSTR2 + kb * 32 + lg * 8]);
      s16x8 pa1 = *reinterpret_cast<const s16x8*>(&sP[(r1 + lr) * PSTR2 + kb * 32 + lg * 8]);
      s16x8 vb0 = *reinterpret_cast<const s16x8*>(&sVt[lr * PSTR + kc]);
      s16x8 vb1 = *reinterpret_cast<const s16x8*>(&sVt[(16 + lr) * PSTR + kc]);
      accO[0][0] = __builtin_amdgcn_mfma_f32_16x16x32_bf16(pa0, vb0, accO[0][0], 0, 0, 0);
      accO[0][1] = __builtin_amdgcn_mfma_f32_16x16x32_bf16(pa0, vb1, accO[0][1], 0, 0, 0);
      accO[1][0] = __builtin_amdgcn_mfma_f32_16x16x32_bf16(pa1, vb0, accO[1][0], 0, 0, 0);
      accO[1][1] = __builtin_amdgcn_mfma_f32_16x16x32_bf16(pa1, vb1, accO[1][1], 0, 0, 0);
    }
  }

  float* opl   = out + (size_t)(b * 8 + d) * HWC;
  ushort* wpl  = ws  + (size_t)(b * 8 + d) * HWC;
  #pragma unroll
  for (int rb = 0; rb < 2; ++rb) {
    #pragma unroll
    for (int r = 0; r < 4; ++r) {
      float s = rsum[rb][r];
      s += __shfl_xor(s, 1); s += __shfl_xor(s, 2);
      s += __shfl_xor(s, 4); s += __shfl_xor(s, 8);
      int tok = (2 * wv + rb) * 16 + lg * 4 + r;
      int g = (tok >> 1) * WC + (wq * 2 + (tok & 1)) * 96 + hc;
      float inv = 1.0f / s;
      if (WSOUT) {
        wpl[g + lr] = f2bf(accO[rb][0][r] * inv);
        if (lr < 8) wpl[g + 16 + lr] = f2bf(accO[rb][1][r] * inv);
      } else {
        opl[g + lr] = accO[rb][0][r] * inv;
        if (lr < 8) opl[g + 16 + lr] = accO[rb][1][r] * inv;
      }
    }
  }
}

// ====== Kernel CB: LePE + MFMA proj — async global_load_lds double-buffer ======
// sV2[2][64*96] linear bf16; per region: issue DMA(r+1 -> other buf), taps(r),
// one barrier (its vmcnt(0) drain completes the DMA). No staging VGPRs ->
// hoist-spill structurally impossible. LDS 50.5KB -> 3 blocks/CU.
constexpr int WSTR = 104;

template <bool WSIN>
__global__ void __launch_bounds__(256, 2)
lepe_proj_fused_kernel(const float* __restrict__ qkv, const float* __restrict__ cw,
                       const float* __restrict__ cbias, const float* __restrict__ pw,
                       const float* __restrict__ pb, float* __restrict__ io,
                       const ushort* __restrict__ ws) {
  __shared__ ushort sV2[2][64 * 96];  // 24576 B (linear: DMA-compatible)
  __shared__ ushort sW[96 * WSTR];    // 19968 B
  __shared__ ushort sCW[27 * 96];     //  5184 B
  __shared__ float  sCB[96];
  __shared__ float  sPB[96];

  const int t   = threadIdx.x;
  const int bid = xswz8(blockIdx.x, 1024);
  const int h   = bid & 63;
  const int d   = (bid >> 6) & 7;
  const int b   = bid >> 9;

  const int wvq = t >> 6, lane = t & 63;

  float* iop = io + (size_t)(b * 8 + d) * HWC + h * WC;
  const ushort* wsp = ws + (size_t)(b * 8 + d) * HWC + h * WC;       // attn rows
  const ushort* wvb = ws + BDHWC + (size_t)b * 8 * HWC;              // V bf16 batch
  const float* vbatch = qkv + 2 * (size_t)BDHWC + (size_t)b * 8 * HWC;

  const int tt  = t >> 2;
  const int cbk = (t & 3) * 24;

  // ---- attn rows: issue reads first ----
  float lep[24];
  if (WSIN) {
    union { s16x8 v; ushort u[8]; } azu[3];
    #pragma unroll
    for (int k = 0; k < 3; ++k)
      azu[k].v = *reinterpret_cast<const s16x8*>(wsp + tt * 96 + cbk + k * 8);
    #pragma unroll
    for (int k = 0; k < 3; ++k)
      #pragma unroll
      for (int e = 0; e < 8; ++e) lep[8*k+e] = bf2f(azu[k].u[e]);
  } else {
    float4 az[6];
    #pragma unroll
    for (int j = 0; j < 6; ++j)
      az[j] = *reinterpret_cast<const float4*>(iop + tt * 96 + cbk + j * 4);
    #pragma unroll
    for (int j = 0; j < 6; ++j) {
      lep[4*j+0] = az[j].x; lep[4*j+1] = az[j].y;
      lep[4*j+2] = az[j].z; lep[4*j+3] = az[j].w;
    }
  }

  // ---- stage weights ----
  #pragma unroll
  for (int it = 0; it < 9; ++it) {
    int idx = t + it * 256;
    int co = idx / 24, c4 = (idx - co * 24) * 4;
    float4 x = *reinterpret_cast<const float4*>(pw + co * 96 + c4);
    ushort4 hx = { f2bf(x.x), f2bf(x.y), f2bf(x.z), f2bf(x.w) };
    *reinterpret_cast<ushort4*>(&sW[co * WSTR + c4]) = hx;
  }
  for (int idx = t; idx < 2592; idx += 256) {
    int c = idx / 27, tap = idx - c * 27;
    sCW[tap * 96 + c] = f2bf(cw[idx]);
  }
  if (t < 96) { sCB[t] = cbias[t]; sPB[t] = pb[t]; }

  // ---- clamped region coords & validity (block-uniform) ----
  int   zdc[3], zhc[3];
  float fdc[3], fhc[3];
  #pragma unroll
  for (int j = 0; j < 3; ++j) {
    int zd = d + j - 1;
    fdc[j] = (zd >= 0 && zd < D_) ? 1.f : 0.f;
    zdc[j] = zd < 0 ? 0 : (zd > D_ - 1 ? D_ - 1 : zd);
    int zh = h + j - 1;
    fhc[j] = (zh >= 0 && zh < H_) ? 1.f : 0.f;
    zhc[j] = zh < 0 ? 0 : (zh > H_ - 1 ? H_ - 1 : zh);
  }
  const float fwl0 = (tt > 0)  ? 1.f : 0.f;
  const float fwl2 = (tt < 63) ? 1.f : 0.f;
  const int   zw0  = (tt > 0)  ? tt - 1 : 0;
  const int   zw2  = (tt < 63) ? tt + 1 : 63;

  #define TAPC(BI, row, tap)                                                 \
    {                                                                        \
      _Pragma("unroll")                                                      \
      for (int j8 = 0; j8 < 3; ++j8) {                                       \
        union { s16x8 v; ushort u[8]; } vu;                                  \
        vu.v = *reinterpret_cast<const s16x8*>(&sV2[BI][(row) * 96 + cbk + j8 * 8]); \
        union { s16x8 v; ushort u[8]; } wu;                                  \
        wu.v = *reinterpret_cast<const s16x8*>(&sCW[(tap) * 96 + cbk + j8 * 8]); \
        _Pragma("unroll")                                                    \
        for (int e = 0; e < 8; ++e)                                          \
          lep[8*j8+e] = fmaf(bf2f(vu.u[e]), bf2f(wu.u[e]), lep[8*j8+e]);     \
      }                                                                      \
    }
  #define TAPE(BI, row, tap, FW)                                             \
    {                                                                        \
      _Pragma("unroll")                                                      \
      for (int j8 = 0; j8 < 3; ++j8) {                                       \
        union { s16x8 v; ushort u[8]; } vu;                                  \
        vu.v = *reinterpret_cast<const s16x8*>(&sV2[BI][(row) * 96 + cbk + j8 * 8]); \
        union { s16x8 v; ushort u[8]; } wu;                                  \
        wu.v = *reinterpret_cast<const s16x8*>(&sCW[(tap) * 96 + cbk + j8 * 8]); \
        _Pragma("unroll")                                                    \
        for (int e = 0; e < 8; ++e)                                          \
          lep[8*j8+e] = fmaf(bf2f(vu.u[e]) * (FW), bf2f(wu.u[e]), lep[8*j8+e]); \
      }                                                                      \
    }
  // async DMA of one V row (12288B): 3 x global_load_lds(16B) per wave
  #define DMA(zd, zh, BI)                                                    \
    {                                                                        \
      const ushort* vrow_ = wvb + (size_t)(zd) * HWC + (zh) * WC;            \
      _Pragma("unroll")                                                      \
      for (int c_ = 0; c_ < 3; ++c_) {                                       \
        int ch_ = c_ * 4 + wvq;                                              \
        __builtin_amdgcn_global_load_lds(                                    \
            (const __attribute__((address_space(1))) void*)(vrow_ + ch_ * 512 + lane * 8), \
            (__attribute__((address_space(3))) void*)(&sV2[BI][ch_ * 512]),  \
            16, 0, 0);                                                       \
      }                                                                      \
    }

  if (WSIN) {
    DMA(zdc[0], zhc[0], 0);     // region 0 -> buf0
    __syncthreads();            // drains vmcnt(0): buf0 ready; weights visible
    #pragma unroll
    for (int r = 0; r < 9; ++r) {
      const int dd = r / 3, dh = r - 3 * dd;
      if (r < 8) {
        const int nr = r + 1, nd = nr / 3, nh = nr - 3 * nd;
        DMA(zdc[nd], zhc[nh], nr & 1);   // flies during taps(r)
      }
      if (fdc[dd] * fhc[dh] != 0.f) {    // block-uniform
        TAPE(r & 1, zw0, r * 3 + 0, fwl0);
        TAPC(r & 1, tt,  r * 3 + 1);
        TAPE(r & 1, zw2, r * 3 + 2, fwl2);
      }
      __syncthreads();                   // taps(r) done + DMA(r+1) complete
    }
  } else {
    // fallback: synchronous staging (fp32 source), single buffer
    #pragma unroll
    for (int dd = 0; dd < 3; ++dd) {
      int zd = d + dd - 1;
      if (zd < 0 || zd >= D_) continue;
      #pragma unroll
      for (int dh = 0; dh < 3; ++dh) {
        int zh = h + dh - 1;
        if (zh < 0 || zh >= H_) continue;
        __syncthreads();
        const float4* src = reinterpret_cast<const float4*>(
            vbatch + (size_t)zd * HWC + zh * WC);
        #pragma unroll
        for (int it = 0; it < 6; ++it) {
          int idx = t + it * 256;
          int tok = idx / 24, c4 = idx - tok * 24;
          float4 x = src[idx];
          ushort4 hx = { f2bf(x.x), f2bf(x.y), f2bf(x.z), f2bf(x.w) };
          *reinterpret_cast<ushort4*>(&sV2[0][tok * 96 + c4 * 4]) = hx;
        }
        __syncthreads();
        const int tap0 = dd * 9 + dh * 3;
        TAPE(0, zw0, tap0 + 0, fwl0);
        TAPC(0, tt,  tap0 + 1);
        TAPE(0, zw2, tap0 + 2, fwl2);
      }
    }
    __syncthreads();
  }
  #undef TAPC
  #undef TAPE
  #undef DMA

  // ---- buffers dead: repack (lep + conv bias) bf16 into sV2[0] ----
  #pragma unroll
  for (int j = 0; j < 6; ++j) {
    float4 bz = *reinterpret_cast<const float4*>(sCB + cbk + j * 4);
    ushort4 hx = { f2bf(lep[4*j+0] + bz.x), f2bf(lep[4*j+1] + bz.y),
                   f2bf(lep[4*j+2] + bz.z), f2bf(lep[4*j+3] + bz.w) };
    *reinterpret_cast<ushort4*>(&sV2[0][tt * 96 + cbk + j * 4]) = hx;
  }
  __syncthreads();

  const int lr = lane & 15, lg = lane >> 4;

  f32x4 acc[6];
  #pragma unroll
  for (int cb = 0; cb < 6; ++cb) {
    float bv = sPB[cb * 16 + lr];
    acc[cb] = f32x4{bv, bv, bv, bv};
  }
  s16x8 afr[3];
  #pragma unroll
  for (int kb = 0; kb < 3; ++kb)
    afr[kb] = *reinterpret_cast<const s16x8*>(&sV2[0][(wvq * 16 + lr) * 96 + kb * 32 + lg * 8]);
  #pragma unroll
  for (int kb = 0; kb < 3; ++kb) {
    #pragma unroll
    for (int cb = 0; cb < 6; ++cb) {
      s16x8 bfr = *reinterpret_cast<const s16x8*>(&sW[(cb * 16 + lr) * WSTR + kb * 32 + lg * 8]);
      acc[cb] = __builtin_amdgcn_mfma_f32_16x16x32_bf16(afr[kb], bfr, acc[cb], 0, 0, 0);
    }
  }

  #pragma unroll
  for (int cb = 0; cb < 6; ++cb) {
    #pragma unroll
    for (int r = 0; r < 4; ++r) {
      int tok = wvq * 16 + lg * 4 + r;
      iop[tok * 96 + cb * 16 + lr] = acc[cb][r];
    }
  }
}

extern "C" void kernel_launch(void* const* d_in, const int* in_sizes, int n_in,
                              void* d_out, int out_size, void* d_ws, size_t ws_size,
                              hipStream_t stream) {
  const float* qkv = (const float*)d_in[0];
  const float* cw  = (const float*)d_in[1];
  const float* cb  = (const float*)d_in[2];
  const float* pw  = (const float*)d_in[3];
  const float* pb  = (const float*)d_in[4];
  float* out = (float*)d_out;
  ushort* ws = (ushort*)d_ws;

  const size_t need = (size_t)2 * BDHWC * sizeof(ushort);  // 25.2 MB
  if (ws_size >= need) {
    hipLaunchKernelGGL((attn_mfma_kernel<true>), dim3(2048), dim3(256), 0, stream,
                       qkv, out, ws);
    hipLaunchKernelGGL((lepe_proj_fused_kernel<true>), dim3(1024), dim3(256), 0, stream,
                       qkv, cw, cb, pw, pb, out, ws);
  } else {
    hipLaunchKernelGGL((attn_mfma_kernel<false>), dim3(2048), dim3(256), 0, stream,
                       qkv, out, ws);
    hipLaunchKernelGGL((lepe_proj_fused_kernel<false>), dim3(1024), dim3(256), 0, stream,
                       qkv, cw, cb, pw, pb, out, ws);
  }
}

// Round 22
// 54.486 us; speedup vs baseline: 1.1400x; 1.0289x over previous
//
#include <hip/hip_runtime.h>
#include <hip/hip_bf16.h>
#include <hip/hip_fp16.h>

constexpr int D_ = 8, H_ = 64, W_ = 64, C_ = 96;
constexpr int WC    = W_ * C_;            // 6144
constexpr int HWC   = H_ * W_ * C_;       // 393216
constexpr int BDHWC = 2 * D_ * HWC;       // 6291456 (elements per tensor)
constexpr float SCALE = 0.10206207261596577f;  // (384/4)^-0.5

typedef __attribute__((ext_vector_type(4))) float f32x4;
typedef __attribute__((ext_vector_type(8))) short s16x8;

__device__ inline ushort f2bf(float x) {
  union { __hip_bfloat16 h; ushort u; } c;
  c.h = __float2bfloat16(x);
  return c.u;
}
__device__ inline float bf2f(ushort u) {
  union { float f; unsigned i; } c;
  c.i = ((unsigned)u) << 16;
  return c.f;
}
__device__ inline ushort f2h(float x) {
  union { __half h; ushort u; } c;
  c.h = __float2half(x);
  return c.u;
}
__device__ inline int xswz8(int bid, int nwg) {
  return (bid & 7) * (nwg >> 3) + (bid >> 3);
}

// ================= Kernel A: MFMA attention, half-P, 37.4KB LDS =================
// WSOUT=1: attn rows bf16 -> ws[0..BDHWC); V fp16 -> ws[BDHWC..2*BDHWC).
constexpr int QSTR  = 40;
constexpr int PSTR  = 136;
constexpr int PSTR2 = 72;

template <bool WSOUT>
__global__ void __launch_bounds__(256, 4)
attn_mfma_kernel(const float* __restrict__ qkv, float* __restrict__ out,
                 ushort* __restrict__ ws) {
  __shared__ ushort sK[128 * QSTR];    // 10240 B
  __shared__ ushort sVt[32 * PSTR];    //  8704 B
  __shared__ ushort sP[128 * PSTR2];   // 18432 B

  const int t    = threadIdx.x;
  const int bid  = xswz8(blockIdx.x, 2048);
  const int head = bid & 3;
  const int nw   = bid >> 2;
  const int wq   = nw & 31;
  const int d    = (nw >> 5) & 7;
  const int b    = nw >> 8;
  const int hc   = head * 24;

  const float* qpl = qkv + (size_t)(b * 8 + d) * HWC;
  const float* kpl = qpl + BDHWC;
  const float* vpl = kpl + BDHWC;
  ushort* wvpl = ws + BDHWC + (size_t)(b * 8 + d) * HWC;   // V fp16 out

  {
    const s16x8 Z = {0, 0, 0, 0, 0, 0, 0, 0};
    int row = t >> 1, col = 24 + (t & 1) * 8;
    *reinterpret_cast<s16x8*>(&sK[row * QSTR + col]) = Z;
    if (t < 136) *reinterpret_cast<s16x8*>(&sVt[24 * PSTR + t * 8]) = Z;
  }

  #pragma unroll
  for (int it = 0; it < 3; ++it) {
    int idx = t + it * 256;
    int tok = idx / 6, c4 = (idx - tok * 6) * 4;
    int g = (tok >> 1) * WC + (wq * 2 + (tok & 1)) * 96 + hc + c4;
    float4 kv = *reinterpret_cast<const float4*>(kpl + g);
    float4 vv = *reinterpret_cast<const float4*>(vpl + g);
    ushort4 kh = { f2bf(kv.x), f2bf(kv.y), f2bf(kv.z), f2bf(kv.w) };
    ushort4 vh = { f2bf(vv.x), f2bf(vv.y), f2bf(vv.z), f2bf(vv.w) };
    *reinterpret_cast<ushort4*>(&sK[tok * QSTR + c4]) = kh;
    sVt[(c4 + 0) * PSTR + tok] = vh.x;
    sVt[(c4 + 1) * PSTR + tok] = vh.y;
    sVt[(c4 + 2) * PSTR + tok] = vh.z;
    sVt[(c4 + 3) * PSTR + tok] = vh.w;
    if (WSOUT) {
      ushort4 vh16 = { f2h(vv.x), f2h(vv.y), f2h(vv.z), f2h(vv.w) };
      *reinterpret_cast<ushort4*>(wvpl + g) = vh16;   // V fp16 handoff
    }
  }

  const int wv = t >> 6, lane = t & 63;
  const int lr = lane & 15;
  const int lg = lane >> 4;
  const int r0 = (2 * wv) * 16;
  const int r1 = (2 * wv + 1) * 16;

  s16x8 a0 = {0,0,0,0,0,0,0,0}, a1 = {0,0,0,0,0,0,0,0};
  if (lg < 3) {
    union { s16x8 v; ushort u[8]; } qa;
    int tok = r0 + lr;
    const float* qp = qpl + (tok >> 1) * WC + (wq * 2 + (tok & 1)) * 96 + hc + lg * 8;
    float4 x0 = *reinterpret_cast<const float4*>(qp);
    float4 x1 = *reinterpret_cast<const float4*>(qp + 4);
    qa.u[0] = f2bf(x0.x * SCALE); qa.u[1] = f2bf(x0.y * SCALE);
    qa.u[2] = f2bf(x0.z * SCALE); qa.u[3] = f2bf(x0.w * SCALE);
    qa.u[4] = f2bf(x1.x * SCALE); qa.u[5] = f2bf(x1.y * SCALE);
    qa.u[6] = f2bf(x1.z * SCALE); qa.u[7] = f2bf(x1.w * SCALE);
    a0 = qa.v;
    tok = r1 + lr;
    qp = qpl + (tok >> 1) * WC + (wq * 2 + (tok & 1)) * 96 + hc + lg * 8;
    x0 = *reinterpret_cast<const float4*>(qp);
    x1 = *reinterpret_cast<const float4*>(qp + 4);
    qa.u[0] = f2bf(x0.x * SCALE); qa.u[1] = f2bf(x0.y * SCALE);
    qa.u[2] = f2bf(x0.z * SCALE); qa.u[3] = f2bf(x0.w * SCALE);
    qa.u[4] = f2bf(x1.x * SCALE); qa.u[5] = f2bf(x1.y * SCALE);
    qa.u[6] = f2bf(x1.z * SCALE); qa.u[7] = f2bf(x1.w * SCALE);
    a1 = qa.v;
  }

  __syncthreads();

  float rsum[2][4];
  #pragma unroll
  for (int rb = 0; rb < 2; ++rb)
    #pragma unroll
    for (int r = 0; r < 4; ++r) rsum[rb][r] = 0.f;

  f32x4 accO[2][2];
  #pragma unroll
  for (int i = 0; i < 2; ++i)
    #pragma unroll
    for (int j = 0; j < 2; ++j) accO[i][j] = f32x4{0.f, 0.f, 0.f, 0.f};

  #pragma unroll
  for (int half = 0; half < 2; ++half) {
    f32x4 accS[2][4];
    #pragma unroll
    for (int i = 0; i < 2; ++i)
      #pragma unroll
      for (int j = 0; j < 4; ++j) accS[i][j] = f32x4{0.f, 0.f, 0.f, 0.f};

    #pragma unroll
    for (int nb = 0; nb < 4; ++nb) {
      s16x8 bb = *reinterpret_cast<const s16x8*>(
          &sK[(half * 64 + nb * 16 + lr) * QSTR + lg * 8]);
      accS[0][nb] = __builtin_amdgcn_mfma_f32_16x16x32_bf16(a0, bb, accS[0][nb], 0, 0, 0);
      accS[1][nb] = __builtin_amdgcn_mfma_f32_16x16x32_bf16(a1, bb, accS[1][nb], 0, 0, 0);
    }

    #pragma unroll
    for (int rb = 0; rb < 2; ++rb)
      #pragma unroll
      for (int nb = 0; nb < 4; ++nb)
        #pragma unroll
        for (int r = 0; r < 4; ++r) {
          float e = __expf(accS[rb][nb][r]);
          accS[rb][nb][r] = e;
          rsum[rb][r] += e;
        }

    if (half) __syncthreads();

    #pragma unroll
    for (int rb = 0; rb < 2; ++rb)
      #pragma unroll
      for (int nb = 0; nb < 4; ++nb)
        #pragma unroll
        for (int r = 0; r < 4; ++r)
          sP[((2 * wv + rb) * 16 + lg * 4 + r) * PSTR2 + nb * 16 + lr] =
              f2bf(accS[rb][nb][r]);
    __syncthreads();

    #pragma unroll
    for (int kb = 0; kb < 2; ++kb) {
      int kc = half * 64 + kb * 32 + lg * 8;
      s16x8 pa0 = *reinterpret_cast<const s16x8*>(&sP[(r0 + lr) * PSTR2 + kb * 32 + lg * 8]);
      s16x8 pa1 = *reinterpret_cast<const s16x8*>(&sP[(r1 + lr) * PSTR2 + kb * 32 + lg * 8]);
      s16x8 vb0 = *reinterpret_cast<const s16x8*>(&sVt[lr * PSTR + kc]);
      s16x8 vb1 = *reinterpret_cast<const s16x8*>(&sVt[(16 + lr) * PSTR + kc]);
      accO[0][0] = __builtin_amdgcn_mfma_f32_16x16x32_bf16(pa0, vb0, accO[0][0], 0, 0, 0);
      accO[0][1] = __builtin_amdgcn_mfma_f32_16x16x32_bf16(pa0, vb1, accO[0][1], 0, 0, 0);
      accO[1][0] = __builtin_amdgcn_mfma_f32_16x16x32_bf16(pa1, vb0, accO[1][0], 0, 0, 0);
      accO[1][1] = __builtin_amdgcn_mfma_f32_16x16x32_bf16(pa1, vb1, accO[1][1], 0, 0, 0);
    }
  }

  float* opl   = out + (size_t)(b * 8 + d) * HWC;
  ushort* wpl  = ws  + (size_t)(b * 8 + d) * HWC;
  #pragma unroll
  for (int rb = 0; rb < 2; ++rb) {
    #pragma unroll
    for (int r = 0; r < 4; ++r) {
      float s = rsum[rb][r];
      s += __shfl_xor(s, 1); s += __shfl_xor(s, 2);
      s += __shfl_xor(s, 4); s += __shfl_xor(s, 8);
      int tok = (2 * wv + rb) * 16 + lg * 4 + r;
      int g = (tok >> 1) * WC + (wq * 2 + (tok & 1)) * 96 + hc;
      float inv = 1.0f / s;
      if (WSOUT) {
        wpl[g + lr] = f2bf(accO[rb][0][r] * inv);
        if (lr < 8) wpl[g + 16 + lr] = f2bf(accO[rb][1][r] * inv);
      } else {
        opl[g + lr] = accO[rb][0][r] * inv;
        if (lr < 8) opl[g + 16 + lr] = accO[rb][1][r] * inv;
      }
    }
  }
}

// ====== Kernel CB: LePE + MFMA proj — async DMA dbuf + fp16 mix-FMA taps ======
// V and conv weights stored fp16; taps use fmaf(h2f(v),h2f(w),f32acc) which
// clang fuses to v_fma_mix_f32 (converts folded, f32 accumulate). Zero-halo
// rows 0/65 in both buffers kill w-edge factor ops; DMA fills rows 1..64
// (dest offset +96, still contiguous). No staging VGPRs -> no spill.
constexpr int WSTR = 104;
constexpr int VROW = 96;    // linear V row stride (halves)
constexpr int VBUF = 66 * VROW;  // 6336 halves per buffer

template <bool WSIN>
__global__ void __launch_bounds__(256, 2)
lepe_proj_fused_kernel(const float* __restrict__ qkv, const float* __restrict__ cw,
                       const float* __restrict__ cbias, const float* __restrict__ pw,
                       const float* __restrict__ pb, float* __restrict__ io,
                       const ushort* __restrict__ ws) {
  __shared__ ushort sV2[2][VBUF];     // 25344 B fp16 (rows 0,65 = zero halo)
  __shared__ ushort sW[96 * WSTR];    // 19968 B bf16 proj weight
  __shared__ ushort sCW[27 * 96];     //  5184 B fp16 conv weights [tap][c]
  __shared__ float  sCB[96];
  __shared__ float  sPB[96];

  const int t   = threadIdx.x;
  const int bid = xswz8(blockIdx.x, 1024);
  const int h   = bid & 63;
  const int d   = (bid >> 6) & 7;
  const int b   = bid >> 9;

  const int wvq = t >> 6, lane = t & 63;

  float* iop = io + (size_t)(b * 8 + d) * HWC + h * WC;
  const ushort* wsp = ws + (size_t)(b * 8 + d) * HWC + h * WC;       // attn rows
  const ushort* wvb = ws + BDHWC + (size_t)b * 8 * HWC;              // V fp16 batch
  const float* vbatch = qkv + 2 * (size_t)BDHWC + (size_t)b * 8 * HWC;

  const int tt  = t >> 2;
  const int cbk = (t & 3) * 24;

  // ---- attn rows: issue reads first ----
  float lep[24];
  if (WSIN) {
    union { s16x8 v; ushort u[8]; } azu[3];
    #pragma unroll
    for (int k = 0; k < 3; ++k)
      azu[k].v = *reinterpret_cast<const s16x8*>(wsp + tt * 96 + cbk + k * 8);
    #pragma unroll
    for (int k = 0; k < 3; ++k)
      #pragma unroll
      for (int e = 0; e < 8; ++e) lep[8*k+e] = bf2f(azu[k].u[e]);
  } else {
    float4 az[6];
    #pragma unroll
    for (int j = 0; j < 6; ++j)
      az[j] = *reinterpret_cast<const float4*>(iop + tt * 96 + cbk + j * 4);
    #pragma unroll
    for (int j = 0; j < 6; ++j) {
      lep[4*j+0] = az[j].x; lep[4*j+1] = az[j].y;
      lep[4*j+2] = az[j].z; lep[4*j+3] = az[j].w;
    }
  }

  // ---- zero halo rows (rows 0,65 of both buffers), once ----
  if (t < 48) {
    const s16x8 Z = {0, 0, 0, 0, 0, 0, 0, 0};
    int buf = t / 24, rr = t - buf * 24;
    int row = (rr < 12) ? 0 : 65;
    int col = (rr < 12 ? rr : rr - 12) * 8;
    *reinterpret_cast<s16x8*>(&sV2[buf][row * VROW + col]) = Z;
  }

  // ---- stage weights ----
  #pragma unroll
  for (int it = 0; it < 9; ++it) {
    int idx = t + it * 256;
    int co = idx / 24, c4 = (idx - co * 24) * 4;
    float4 x = *reinterpret_cast<const float4*>(pw + co * 96 + c4);
    ushort4 hx = { f2bf(x.x), f2bf(x.y), f2bf(x.z), f2bf(x.w) };
    *reinterpret_cast<ushort4*>(&sW[co * WSTR + c4]) = hx;
  }
  for (int idx = t; idx < 2592; idx += 256) {
    int c = idx / 27, tap = idx - c * 27;
    sCW[tap * 96 + c] = f2h(cw[idx]);    // fp16 conv weights
  }
  if (t < 96) { sCB[t] = cbias[t]; sPB[t] = pb[t]; }

  // ---- clamped region coords & validity (block-uniform) ----
  int   zdc[3], zhc[3];
  float fdc[3], fhc[3];
  #pragma unroll
  for (int j = 0; j < 3; ++j) {
    int zd = d + j - 1;
    fdc[j] = (zd >= 0 && zd < D_) ? 1.f : 0.f;
    zdc[j] = zd < 0 ? 0 : (zd > D_ - 1 ? D_ - 1 : zd);
    int zh = h + j - 1;
    fhc[j] = (zh >= 0 && zh < H_) ? 1.f : 0.f;
    zhc[j] = zh < 0 ? 0 : (zh > H_ - 1 ? H_ - 1 : zh);
  }

  // fp16 mix-FMA tap: fmaf(h2f(v), h2f(w), f32) -> v_fma_mix_f32
  #define TAP(BI, row, tap)                                                  \
    {                                                                        \
      _Pragma("unroll")                                                      \
      for (int j8 = 0; j8 < 3; ++j8) {                                       \
        union { s16x8 v; __half u[8]; } vu;                                  \
        vu.v = *reinterpret_cast<const s16x8*>(&sV2[BI][(row) * VROW + cbk + j8 * 8]); \
        union { s16x8 v; __half u[8]; } wu;                                  \
        wu.v = *reinterpret_cast<const s16x8*>(&sCW[(tap) * 96 + cbk + j8 * 8]); \
        _Pragma("unroll")                                                    \
        for (int e = 0; e < 8; ++e)                                          \
          lep[8*j8+e] = fmaf(__half2float(vu.u[e]), __half2float(wu.u[e]),   \
                             lep[8*j8+e]);                                   \
      }                                                                      \
    }
  // async DMA of one V row (12288B) into rows 1..64 of buffer BI
  #define DMA(zd, zh, BI)                                                    \
    {                                                                        \
      const ushort* vrow_ = wvb + (size_t)(zd) * HWC + (zh) * WC;            \
      _Pragma("unroll")                                                      \
      for (int c_ = 0; c_ < 3; ++c_) {                                       \
        int ch_ = c_ * 4 + wvq;                                              \
        __builtin_amdgcn_global_load_lds(                                    \
            (const __attribute__((address_space(1))) void*)(vrow_ + ch_ * 512 + lane * 8), \
            (__attribute__((address_space(3))) void*)(&sV2[BI][VROW + ch_ * 512]), \
            16, 0, 0);                                                       \
      }                                                                      \
    }

  if (WSIN) {
    DMA(zdc[0], zhc[0], 0);     // region 0 -> buf0
    __syncthreads();            // vmcnt(0) drain: buf0 + halo + weights ready
    #pragma unroll
    for (int r = 0; r < 9; ++r) {
      const int dd = r / 3, dh = r - 3 * dd;
      if (r < 8) {
        const int nr = r + 1, nd = nr / 3, nh = nr - 3 * nd;
        DMA(zdc[nd], zhc[nh], nr & 1);   // flies during taps(r)
      }
      if (fdc[dd] * fhc[dh] != 0.f) {    // block-uniform region validity
        TAP(r & 1, tt,     r * 3 + 0);
        TAP(r & 1, tt + 1, r * 3 + 1);
        TAP(r & 1, tt + 2, r * 3 + 2);
      }
      __syncthreads();                   // taps(r) done + DMA(r+1) complete
    }
  } else {
    // fallback: synchronous staging (fp32 source -> fp16), single buffer
    #pragma unroll
    for (int dd = 0; dd < 3; ++dd) {
      int zd = d + dd - 1;
      if (zd < 0 || zd >= D_) continue;
      #pragma unroll
      for (int dh = 0; dh < 3; ++dh) {
        int zh = h + dh - 1;
        if (zh < 0 || zh >= H_) continue;
        __syncthreads();
        const float4* src = reinterpret_cast<const float4*>(
            vbatch + (size_t)zd * HWC + zh * WC);
        #pragma unroll
        for (int it = 0; it < 6; ++it) {
          int idx = t + it * 256;
          int tok = idx / 24, c4 = idx - tok * 24;
          float4 x = src[idx];
          ushort4 hx = { f2h(x.x), f2h(x.y), f2h(x.z), f2h(x.w) };
          *reinterpret_cast<ushort4*>(&sV2[0][(tok + 1) * VROW + c4 * 4]) = hx;
        }
        __syncthreads();
        const int tap0 = dd * 9 + dh * 3;
        TAP(0, tt,     tap0 + 0);
        TAP(0, tt + 1, tap0 + 1);
        TAP(0, tt + 2, tap0 + 2);
      }
    }
    __syncthreads();
  }
  #undef TAP
  #undef DMA

  // ---- buffers dead: repack (lep + conv bias) bf16 into sV2[0] ----
  #pragma unroll
  for (int j = 0; j < 6; ++j) {
    float4 bz = *reinterpret_cast<const float4*>(sCB + cbk + j * 4);
    ushort4 hx = { f2bf(lep[4*j+0] + bz.x), f2bf(lep[4*j+1] + bz.y),
                   f2bf(lep[4*j+2] + bz.z), f2bf(lep[4*j+3] + bz.w) };
    *reinterpret_cast<ushort4*>(&sV2[0][tt * 96 + cbk + j * 4]) = hx;
  }
  __syncthreads();

  const int lr = lane & 15, lg = lane >> 4;

  f32x4 acc[6];
  #pragma unroll
  for (int cb = 0; cb < 6; ++cb) {
    float bv = sPB[cb * 16 + lr];
    acc[cb] = f32x4{bv, bv, bv, bv};
  }
  s16x8 afr[3];
  #pragma unroll
  for (int kb = 0; kb < 3; ++kb)
    afr[kb] = *reinterpret_cast<const s16x8*>(&sV2[0][(wvq * 16 + lr) * 96 + kb * 32 + lg * 8]);
  #pragma unroll
  for (int kb = 0; kb < 3; ++kb) {
    #pragma unroll
    for (int cb = 0; cb < 6; ++cb) {
      s16x8 bfr = *reinterpret_cast<const s16x8*>(&sW[(cb * 16 + lr) * WSTR + kb * 32 + lg * 8]);
      acc[cb] = __builtin_amdgcn_mfma_f32_16x16x32_bf16(afr[kb], bfr, acc[cb], 0, 0, 0);
    }
  }

  #pragma unroll
  for (int cb = 0; cb < 6; ++cb) {
    #pragma unroll
    for (int r = 0; r < 4; ++r) {
      int tok = wvq * 16 + lg * 4 + r;
      iop[tok * 96 + cb * 16 + lr] = acc[cb][r];
    }
  }
}

extern "C" void kernel_launch(void* const* d_in, const int* in_sizes, int n_in,
                              void* d_out, int out_size, void* d_ws, size_t ws_size,
                              hipStream_t stream) {
  const float* qkv = (const float*)d_in[0];
  const float* cw  = (const float*)d_in[1];
  const float* cb  = (const float*)d_in[2];
  const float* pw  = (const float*)d_in[3];
  const float* pb  = (const float*)d_in[4];
  float* out = (float*)d_out;
  ushort* ws = (ushort*)d_ws;

  const size_t need = (size_t)2 * BDHWC * sizeof(ushort);  // 25.2 MB
  if (ws_size >= need) {
    hipLaunchKernelGGL((attn_mfma_kernel<true>), dim3(2048), dim3(256), 0, stream,
                       qkv, out, ws);
    hipLaunchKernelGGL((lepe_proj_fused_kernel<true>), dim3(1024), dim3(256), 0, stream,
                       qkv, cw, cb, pw, pb, out, ws);
  } else {
    hipLaunchKernelGGL((attn_mfma_kernel<false>), dim3(2048), dim3(256), 0, stream,
                       qkv, out, ws);
    hipLaunchKernelGGL((lepe_proj_fused_kernel<false>), dim3(1024), dim3(256), 0, stream,
                       qkv, cw, cb, pw, pb, out, ws);
  }
}

// Round 23
// 54.132 us; speedup vs baseline: 1.1474x; 1.0065x over previous
//
#include <hip/hip_runtime.h>
#include <hip/hip_bf16.h>
#include <hip/hip_fp16.h>

constexpr int D_ = 8, H_ = 64, W_ = 64, C_ = 96;
constexpr int WC    = W_ * C_;            // 6144
constexpr int HWC   = H_ * W_ * C_;       // 393216
constexpr int BDHWC = 2 * D_ * HWC;       // 6291456 (elements per tensor)
constexpr float SCALE = 0.10206207261596577f;  // (384/4)^-0.5

typedef __attribute__((ext_vector_type(4))) float f32x4;
typedef __attribute__((ext_vector_type(8))) short s16x8;

__device__ inline ushort f2bf(float x) {
  union { __hip_bfloat16 h; ushort u; } c;
  c.h = __float2bfloat16(x);
  return c.u;
}
__device__ inline float bf2f(ushort u) {
  union { float f; unsigned i; } c;
  c.i = ((unsigned)u) << 16;
  return c.f;
}
__device__ inline ushort f2h(float x) {
  union { __half h; ushort u; } c;
  c.h = __float2half(x);
  return c.u;
}
__device__ inline int xswz8(int bid, int nwg) {
  return (bid & 7) * (nwg >> 3) + (bid >> 3);
}

// ================= Kernel A: MFMA attention, half-P, 37.4KB LDS =================
// WSOUT=1: attn rows bf16 -> ws[0..BDHWC); V fp16 -> ws[BDHWC..2*BDHWC).
// Epilogue: results staged through dead sP -> coalesced ushort4 stores.
constexpr int QSTR  = 40;
constexpr int PSTR  = 136;
constexpr int PSTR2 = 72;

template <bool WSOUT>
__global__ void __launch_bounds__(256, 4)
attn_mfma_kernel(const float* __restrict__ qkv, float* __restrict__ out,
                 ushort* __restrict__ ws) {
  __shared__ ushort sK[128 * QSTR];    // 10240 B
  __shared__ ushort sVt[32 * PSTR];    //  8704 B
  __shared__ ushort sP[128 * PSTR2];   // 18432 B (reused as output stage)

  const int t    = threadIdx.x;
  const int bid  = xswz8(blockIdx.x, 2048);
  const int head = bid & 3;
  const int nw   = bid >> 2;
  const int wq   = nw & 31;
  const int d    = (nw >> 5) & 7;
  const int b    = nw >> 8;
  const int hc   = head * 24;

  const float* qpl = qkv + (size_t)(b * 8 + d) * HWC;
  const float* kpl = qpl + BDHWC;
  const float* vpl = kpl + BDHWC;
  ushort* wvpl = ws + BDHWC + (size_t)(b * 8 + d) * HWC;   // V fp16 out

  {
    const s16x8 Z = {0, 0, 0, 0, 0, 0, 0, 0};
    int row = t >> 1, col = 24 + (t & 1) * 8;
    *reinterpret_cast<s16x8*>(&sK[row * QSTR + col]) = Z;
    if (t < 136) *reinterpret_cast<s16x8*>(&sVt[24 * PSTR + t * 8]) = Z;
  }

  #pragma unroll
  for (int it = 0; it < 3; ++it) {
    int idx = t + it * 256;
    int tok = idx / 6, c4 = (idx - tok * 6) * 4;
    int g = (tok >> 1) * WC + (wq * 2 + (tok & 1)) * 96 + hc + c4;
    float4 kv = *reinterpret_cast<const float4*>(kpl + g);
    float4 vv = *reinterpret_cast<const float4*>(vpl + g);
    ushort4 kh = { f2bf(kv.x), f2bf(kv.y), f2bf(kv.z), f2bf(kv.w) };
    ushort4 vh = { f2bf(vv.x), f2bf(vv.y), f2bf(vv.z), f2bf(vv.w) };
    *reinterpret_cast<ushort4*>(&sK[tok * QSTR + c4]) = kh;
    sVt[(c4 + 0) * PSTR + tok] = vh.x;
    sVt[(c4 + 1) * PSTR + tok] = vh.y;
    sVt[(c4 + 2) * PSTR + tok] = vh.z;
    sVt[(c4 + 3) * PSTR + tok] = vh.w;
    if (WSOUT) {
      ushort4 vh16 = { f2h(vv.x), f2h(vv.y), f2h(vv.z), f2h(vv.w) };
      *reinterpret_cast<ushort4*>(wvpl + g) = vh16;   // V fp16 handoff
    }
  }

  const int wv = t >> 6, lane = t & 63;
  const int lr = lane & 15;
  const int lg = lane >> 4;
  const int r0 = (2 * wv) * 16;
  const int r1 = (2 * wv + 1) * 16;

  s16x8 a0 = {0,0,0,0,0,0,0,0}, a1 = {0,0,0,0,0,0,0,0};
  if (lg < 3) {
    union { s16x8 v; ushort u[8]; } qa;
    int tok = r0 + lr;
    const float* qp = qpl + (tok >> 1) * WC + (wq * 2 + (tok & 1)) * 96 + hc + lg * 8;
    float4 x0 = *reinterpret_cast<const float4*>(qp);
    float4 x1 = *reinterpret_cast<const float4*>(qp + 4);
    qa.u[0] = f2bf(x0.x * SCALE); qa.u[1] = f2bf(x0.y * SCALE);
    qa.u[2] = f2bf(x0.z * SCALE); qa.u[3] = f2bf(x0.w * SCALE);
    qa.u[4] = f2bf(x1.x * SCALE); qa.u[5] = f2bf(x1.y * SCALE);
    qa.u[6] = f2bf(x1.z * SCALE); qa.u[7] = f2bf(x1.w * SCALE);
    a0 = qa.v;
    tok = r1 + lr;
    qp = qpl + (tok >> 1) * WC + (wq * 2 + (tok & 1)) * 96 + hc + lg * 8;
    x0 = *reinterpret_cast<const float4*>(qp);
    x1 = *reinterpret_cast<const float4*>(qp + 4);
    qa.u[0] = f2bf(x0.x * SCALE); qa.u[1] = f2bf(x0.y * SCALE);
    qa.u[2] = f2bf(x0.z * SCALE); qa.u[3] = f2bf(x0.w * SCALE);
    qa.u[4] = f2bf(x1.x * SCALE); qa.u[5] = f2bf(x1.y * SCALE);
    qa.u[6] = f2bf(x1.z * SCALE); qa.u[7] = f2bf(x1.w * SCALE);
    a1 = qa.v;
  }

  __syncthreads();

  float rsum[2][4];
  #pragma unroll
  for (int rb = 0; rb < 2; ++rb)
    #pragma unroll
    for (int r = 0; r < 4; ++r) rsum[rb][r] = 0.f;

  f32x4 accO[2][2];
  #pragma unroll
  for (int i = 0; i < 2; ++i)
    #pragma unroll
    for (int j = 0; j < 2; ++j) accO[i][j] = f32x4{0.f, 0.f, 0.f, 0.f};

  #pragma unroll
  for (int half = 0; half < 2; ++half) {
    f32x4 accS[2][4];
    #pragma unroll
    for (int i = 0; i < 2; ++i)
      #pragma unroll
      for (int j = 0; j < 4; ++j) accS[i][j] = f32x4{0.f, 0.f, 0.f, 0.f};

    #pragma unroll
    for (int nb = 0; nb < 4; ++nb) {
      s16x8 bb = *reinterpret_cast<const s16x8*>(
          &sK[(half * 64 + nb * 16 + lr) * QSTR + lg * 8]);
      accS[0][nb] = __builtin_amdgcn_mfma_f32_16x16x32_bf16(a0, bb, accS[0][nb], 0, 0, 0);
      accS[1][nb] = __builtin_amdgcn_mfma_f32_16x16x32_bf16(a1, bb, accS[1][nb], 0, 0, 0);
    }

    #pragma unroll
    for (int rb = 0; rb < 2; ++rb)
      #pragma unroll
      for (int nb = 0; nb < 4; ++nb)
        #pragma unroll
        for (int r = 0; r < 4; ++r) {
          float e = __expf(accS[rb][nb][r]);
          accS[rb][nb][r] = e;
          rsum[rb][r] += e;
        }

    if (half) __syncthreads();

    #pragma unroll
    for (int rb = 0; rb < 2; ++rb)
      #pragma unroll
      for (int nb = 0; nb < 4; ++nb)
        #pragma unroll
        for (int r = 0; r < 4; ++r)
          sP[((2 * wv + rb) * 16 + lg * 4 + r) * PSTR2 + nb * 16 + lr] =
              f2bf(accS[rb][nb][r]);
    __syncthreads();

    #pragma unroll
    for (int kb = 0; kb < 2; ++kb) {
      int kc = half * 64 + kb * 32 + lg * 8;
      s16x8 pa0 = *reinterpret_cast<const s16x8*>(&sP[(r0 + lr) * PSTR2 + kb * 32 + lg * 8]);
      s16x8 pa1 = *reinterpret_cast<const s16x8*>(&sP[(r1 + lr) * PSTR2 + kb * 32 + lg * 8]);
      s16x8 vb0 = *reinterpret_cast<const s16x8*>(&sVt[lr * PSTR + kc]);
      s16x8 vb1 = *reinterpret_cast<const s16x8*>(&sVt[(16 + lr) * PSTR + kc]);
      accO[0][0] = __builtin_amdgcn_mfma_f32_16x16x32_bf16(pa0, vb0, accO[0][0], 0, 0, 0);
      accO[0][1] = __builtin_amdgcn_mfma_f32_16x16x32_bf16(pa0, vb1, accO[0][1], 0, 0, 0);
      accO[1][0] = __builtin_amdgcn_mfma_f32_16x16x32_bf16(pa1, vb0, accO[1][0], 0, 0, 0);
      accO[1][1] = __builtin_amdgcn_mfma_f32_16x16x32_bf16(pa1, vb1, accO[1][1], 0, 0, 0);
    }
  }

  // ---- row-sum reduce ----
  float invs[2][4];
  #pragma unroll
  for (int rb = 0; rb < 2; ++rb) {
    #pragma unroll
    for (int r = 0; r < 4; ++r) {
      float s = rsum[rb][r];
      s += __shfl_xor(s, 1); s += __shfl_xor(s, 2);
      s += __shfl_xor(s, 4); s += __shfl_xor(s, 8);
      invs[rb][r] = 1.0f / s;
    }
  }

  if (WSOUT) {
    // ---- coalesced epilogue: stage bf16 into dead sP [tok][24], then ushort4 ----
    __syncthreads();   // last PV reads of sP done
    #pragma unroll
    for (int rb = 0; rb < 2; ++rb)
      #pragma unroll
      for (int r = 0; r < 4; ++r) {
        int tok = (2 * wv + rb) * 16 + lg * 4 + r;
        float inv = invs[rb][r];
        sP[tok * 24 + lr] = f2bf(accO[rb][0][r] * inv);
        if (lr < 8) sP[tok * 24 + 16 + lr] = f2bf(accO[rb][1][r] * inv);
      }
    __syncthreads();
    ushort* wpl = ws + (size_t)(b * 8 + d) * HWC;
    #pragma unroll
    for (int it = 0; it < 3; ++it) {
      int idx = t + it * 256;                 // 768 ushort4 chunks
      int tok = idx / 6, c4 = (idx - tok * 6) * 4;
      int g = (tok >> 1) * WC + (wq * 2 + (tok & 1)) * 96 + hc + c4;
      *reinterpret_cast<ushort4*>(wpl + g) =
          *reinterpret_cast<const ushort4*>(&sP[tok * 24 + c4]);
    }
  } else {
    float* opl = out + (size_t)(b * 8 + d) * HWC;
    #pragma unroll
    for (int rb = 0; rb < 2; ++rb) {
      #pragma unroll
      for (int r = 0; r < 4; ++r) {
        int tok = (2 * wv + rb) * 16 + lg * 4 + r;
        int g = (tok >> 1) * WC + (wq * 2 + (tok & 1)) * 96 + hc;
        float inv = invs[rb][r];
        opl[g + lr] = accO[rb][0][r] * inv;
        if (lr < 8) opl[g + 16 + lr] = accO[rb][1][r] * inv;
      }
    }
  }
}

// ====== Kernel CB: LePE + MFMA proj — async DMA dbuf + fp16 mix-FMA taps ======
// (unchanged from r22)
constexpr int WSTR = 104;
constexpr int VROW = 96;
constexpr int VBUF = 66 * VROW;

template <bool WSIN>
__global__ void __launch_bounds__(256, 2)
lepe_proj_fused_kernel(const float* __restrict__ qkv, const float* __restrict__ cw,
                       const float* __restrict__ cbias, const float* __restrict__ pw,
                       const float* __restrict__ pb, float* __restrict__ io,
                       const ushort* __restrict__ ws) {
  __shared__ ushort sV2[2][VBUF];     // 25344 B fp16 (rows 0,65 = zero halo)
  __shared__ ushort sW[96 * WSTR];    // 19968 B bf16 proj weight
  __shared__ ushort sCW[27 * 96];     //  5184 B fp16 conv weights [tap][c]
  __shared__ float  sCB[96];
  __shared__ float  sPB[96];

  const int t   = threadIdx.x;
  const int bid = xswz8(blockIdx.x, 1024);
  const int h   = bid & 63;
  const int d   = (bid >> 6) & 7;
  const int b   = bid >> 9;

  const int wvq = t >> 6, lane = t & 63;

  float* iop = io + (size_t)(b * 8 + d) * HWC + h * WC;
  const ushort* wsp = ws + (size_t)(b * 8 + d) * HWC + h * WC;
  const ushort* wvb = ws + BDHWC + (size_t)b * 8 * HWC;
  const float* vbatch = qkv + 2 * (size_t)BDHWC + (size_t)b * 8 * HWC;

  const int tt  = t >> 2;
  const int cbk = (t & 3) * 24;

  float lep[24];
  if (WSIN) {
    union { s16x8 v; ushort u[8]; } azu[3];
    #pragma unroll
    for (int k = 0; k < 3; ++k)
      azu[k].v = *reinterpret_cast<const s16x8*>(wsp + tt * 96 + cbk + k * 8);
    #pragma unroll
    for (int k = 0; k < 3; ++k)
      #pragma unroll
      for (int e = 0; e < 8; ++e) lep[8*k+e] = bf2f(azu[k].u[e]);
  } else {
    float4 az[6];
    #pragma unroll
    for (int j = 0; j < 6; ++j)
      az[j] = *reinterpret_cast<const float4*>(iop + tt * 96 + cbk + j * 4);
    #pragma unroll
    for (int j = 0; j < 6; ++j) {
      lep[4*j+0] = az[j].x; lep[4*j+1] = az[j].y;
      lep[4*j+2] = az[j].z; lep[4*j+3] = az[j].w;
    }
  }

  if (t < 48) {
    const s16x8 Z = {0, 0, 0, 0, 0, 0, 0, 0};
    int buf = t / 24, rr = t - buf * 24;
    int row = (rr < 12) ? 0 : 65;
    int col = (rr < 12 ? rr : rr - 12) * 8;
    *reinterpret_cast<s16x8*>(&sV2[buf][row * VROW + col]) = Z;
  }

  #pragma unroll
  for (int it = 0; it < 9; ++it) {
    int idx = t + it * 256;
    int co = idx / 24, c4 = (idx - co * 24) * 4;
    float4 x = *reinterpret_cast<const float4*>(pw + co * 96 + c4);
    ushort4 hx = { f2bf(x.x), f2bf(x.y), f2bf(x.z), f2bf(x.w) };
    *reinterpret_cast<ushort4*>(&sW[co * WSTR + c4]) = hx;
  }
  for (int idx = t; idx < 2592; idx += 256) {
    int c = idx / 27, tap = idx - c * 27;
    sCW[tap * 96 + c] = f2h(cw[idx]);
  }
  if (t < 96) { sCB[t] = cbias[t]; sPB[t] = pb[t]; }

  int   zdc[3], zhc[3];
  float fdc[3], fhc[3];
  #pragma unroll
  for (int j = 0; j < 3; ++j) {
    int zd = d + j - 1;
    fdc[j] = (zd >= 0 && zd < D_) ? 1.f : 0.f;
    zdc[j] = zd < 0 ? 0 : (zd > D_ - 1 ? D_ - 1 : zd);
    int zh = h + j - 1;
    fhc[j] = (zh >= 0 && zh < H_) ? 1.f : 0.f;
    zhc[j] = zh < 0 ? 0 : (zh > H_ - 1 ? H_ - 1 : zh);
  }

  #define TAP(BI, row, tap)                                                  \
    {                                                                        \
      _Pragma("unroll")                                                      \
      for (int j8 = 0; j8 < 3; ++j8) {                                       \
        union { s16x8 v; __half u[8]; } vu;                                  \
        vu.v = *reinterpret_cast<const s16x8*>(&sV2[BI][(row) * VROW + cbk + j8 * 8]); \
        union { s16x8 v; __half u[8]; } wu;                                  \
        wu.v = *reinterpret_cast<const s16x8*>(&sCW[(tap) * 96 + cbk + j8 * 8]); \
        _Pragma("unroll")                                                    \
        for (int e = 0; e < 8; ++e)                                          \
          lep[8*j8+e] = fmaf(__half2float(vu.u[e]), __half2float(wu.u[e]),   \
                             lep[8*j8+e]);                                   \
      }                                                                      \
    }
  #define DMA(zd, zh, BI)                                                    \
    {                                                                        \
      const ushort* vrow_ = wvb + (size_t)(zd) * HWC + (zh) * WC;            \
      _Pragma("unroll")                                                      \
      for (int c_ = 0; c_ < 3; ++c_) {                                       \
        int ch_ = c_ * 4 + wvq;                                              \
        __builtin_amdgcn_global_load_lds(                                    \
            (const __attribute__((address_space(1))) void*)(vrow_ + ch_ * 512 + lane * 8), \
            (__attribute__((address_space(3))) void*)(&sV2[BI][VROW + ch_ * 512]), \
            16, 0, 0);                                                       \
      }                                                                      \
    }

  if (WSIN) {
    DMA(zdc[0], zhc[0], 0);
    __syncthreads();
    #pragma unroll
    for (int r = 0; r < 9; ++r) {
      const int dd = r / 3, dh = r - 3 * dd;
      if (r < 8) {
        const int nr = r + 1, nd = nr / 3, nh = nr - 3 * nd;
        DMA(zdc[nd], zhc[nh], nr & 1);
      }
      if (fdc[dd] * fhc[dh] != 0.f) {
        TAP(r & 1, tt,     r * 3 + 0);
        TAP(r & 1, tt + 1, r * 3 + 1);
        TAP(r & 1, tt + 2, r * 3 + 2);
      }
      __syncthreads();
    }
  } else {
    #pragma unroll
    for (int dd = 0; dd < 3; ++dd) {
      int zd = d + dd - 1;
      if (zd < 0 || zd >= D_) continue;
      #pragma unroll
      for (int dh = 0; dh < 3; ++dh) {
        int zh = h + dh - 1;
        if (zh < 0 || zh >= H_) continue;
        __syncthreads();
        const float4* src = reinterpret_cast<const float4*>(
            vbatch + (size_t)zd * HWC + zh * WC);
        #pragma unroll
        for (int it = 0; it < 6; ++it) {
          int idx = t + it * 256;
          int tok = idx / 24, c4 = idx - tok * 24;
          float4 x = src[idx];
          ushort4 hx = { f2h(x.x), f2h(x.y), f2h(x.z), f2h(x.w) };
          *reinterpret_cast<ushort4*>(&sV2[0][(tok + 1) * VROW + c4 * 4]) = hx;
        }
        __syncthreads();
        const int tap0 = dd * 9 + dh * 3;
        TAP(0, tt,     tap0 + 0);
        TAP(0, tt + 1, tap0 + 1);
        TAP(0, tt + 2, tap0 + 2);
      }
    }
    __syncthreads();
  }
  #undef TAP
  #undef DMA

  #pragma unroll
  for (int j = 0; j < 6; ++j) {
    float4 bz = *reinterpret_cast<const float4*>(sCB + cbk + j * 4);
    ushort4 hx = { f2bf(lep[4*j+0] + bz.x), f2bf(lep[4*j+1] + bz.y),
                   f2bf(lep[4*j+2] + bz.z), f2bf(lep[4*j+3] + bz.w) };
    *reinterpret_cast<ushort4*>(&sV2[0][tt * 96 + cbk + j * 4]) = hx;
  }
  __syncthreads();

  const int lr = lane & 15, lg = lane >> 4;

  f32x4 acc[6];
  #pragma unroll
  for (int cb = 0; cb < 6; ++cb) {
    float bv = sPB[cb * 16 + lr];
    acc[cb] = f32x4{bv, bv, bv, bv};
  }
  s16x8 afr[3];
  #pragma unroll
  for (int kb = 0; kb < 3; ++kb)
    afr[kb] = *reinterpret_cast<const s16x8*>(&sV2[0][(wvq * 16 + lr) * 96 + kb * 32 + lg * 8]);
  #pragma unroll
  for (int kb = 0; kb < 3; ++kb) {
    #pragma unroll
    for (int cb = 0; cb < 6; ++cb) {
      s16x8 bfr = *reinterpret_cast<const s16x8*>(&sW[(cb * 16 + lr) * WSTR + kb * 32 + lg * 8]);
      acc[cb] = __builtin_amdgcn_mfma_f32_16x16x32_bf16(afr[kb], bfr, acc[cb], 0, 0, 0);
    }
  }

  #pragma unroll
  for (int cb = 0; cb < 6; ++cb) {
    #pragma unroll
    for (int r = 0; r < 4; ++r) {
      int tok = wvq * 16 + lg * 4 + r;
      iop[tok * 96 + cb * 16 + lr] = acc[cb][r];
    }
  }
}

extern "C" void kernel_launch(void* const* d_in, const int* in_sizes, int n_in,
                              void* d_out, int out_size, void* d_ws, size_t ws_size,
                              hipStream_t stream) {
  const float* qkv = (const float*)d_in[0];
  const float* cw  = (const float*)d_in[1];
  const float* cb  = (const float*)d_in[2];
  const float* pw  = (const float*)d_in[3];
  const float* pb  = (const float*)d_in[4];
  float* out = (float*)d_out;
  ushort* ws = (ushort*)d_ws;

  const size_t need = (size_t)2 * BDHWC * sizeof(ushort);  // 25.2 MB
  if (ws_size >= need) {
    hipLaunchKernelGGL((attn_mfma_kernel<true>), dim3(2048), dim3(256), 0, stream,
                       qkv, out, ws);
    hipLaunchKernelGGL((lepe_proj_fused_kernel<true>), dim3(1024), dim3(256), 0, stream,
                       qkv, cw, cb, pw, pb, out, ws);
  } else {
    hipLaunchKernelGGL((attn_mfma_kernel<false>), dim3(2048), dim3(256), 0, stream,
                       qkv, out, ws);
    hipLaunchKernelGGL((lepe_proj_fused_kernel<false>), dim3(1024), dim3(256), 0, stream,
                       qkv, cw, cb, pw, pb, out, ws);
  }
}

// Round 24
// 53.701 us; speedup vs baseline: 1.1567x; 1.0080x over previous
//
#include <hip/hip_runtime.h>
#include <hip/hip_bf16.h>
#include <hip/hip_fp16.h>

constexpr int D_ = 8, H_ = 64, W_ = 64, C_ = 96;
constexpr int WC    = W_ * C_;            // 6144
constexpr int HWC   = H_ * W_ * C_;       // 393216
constexpr int BDHWC = 2 * D_ * HWC;       // 6291456 (elements per tensor)
constexpr float SCALE = 0.10206207261596577f;  // (384/4)^-0.5

typedef __attribute__((ext_vector_type(4))) float f32x4;
typedef __attribute__((ext_vector_type(8))) short s16x8;

__device__ inline ushort f2bf(float x) {
  union { __hip_bfloat16 h; ushort u; } c;
  c.h = __float2bfloat16(x);
  return c.u;
}
__device__ inline float bf2f(ushort u) {
  union { float f; unsigned i; } c;
  c.i = ((unsigned)u) << 16;
  return c.f;
}
__device__ inline ushort f2h(float x) {
  union { __half h; ushort u; } c;
  c.h = __float2half(x);
  return c.u;
}
__device__ inline int xswz8(int bid, int nwg) {
  return (bid & 7) * (nwg >> 3) + (bid >> 3);
}

// ================= Kernel A: MFMA attention, half-P, 37.4KB LDS =================
// WSOUT=1: attn rows bf16 -> ws[0..BDHWC); V fp16 -> ws[BDHWC..2*BDHWC).
// Epilogue: results staged through dead sP -> coalesced ushort4 stores.
constexpr int QSTR  = 40;
constexpr int PSTR  = 136;
constexpr int PSTR2 = 72;

template <bool WSOUT>
__global__ void __launch_bounds__(256, 4)
attn_mfma_kernel(const float* __restrict__ qkv, float* __restrict__ out,
                 ushort* __restrict__ ws) {
  __shared__ ushort sK[128 * QSTR];    // 10240 B
  __shared__ ushort sVt[32 * PSTR];    //  8704 B
  __shared__ ushort sP[128 * PSTR2];   // 18432 B (reused as output stage)

  const int t    = threadIdx.x;
  const int bid  = xswz8(blockIdx.x, 2048);
  const int head = bid & 3;
  const int nw   = bid >> 2;
  const int wq   = nw & 31;
  const int d    = (nw >> 5) & 7;
  const int b    = nw >> 8;
  const int hc   = head * 24;

  const float* qpl = qkv + (size_t)(b * 8 + d) * HWC;
  const float* kpl = qpl + BDHWC;
  const float* vpl = kpl + BDHWC;
  ushort* wvpl = ws + BDHWC + (size_t)(b * 8 + d) * HWC;   // V fp16 out

  {
    const s16x8 Z = {0, 0, 0, 0, 0, 0, 0, 0};
    int row = t >> 1, col = 24 + (t & 1) * 8;
    *reinterpret_cast<s16x8*>(&sK[row * QSTR + col]) = Z;
    if (t < 136) *reinterpret_cast<s16x8*>(&sVt[24 * PSTR + t * 8]) = Z;
  }

  #pragma unroll
  for (int it = 0; it < 3; ++it) {
    int idx = t + it * 256;
    int tok = idx / 6, c4 = (idx - tok * 6) * 4;
    int g = (tok >> 1) * WC + (wq * 2 + (tok & 1)) * 96 + hc + c4;
    float4 kv = *reinterpret_cast<const float4*>(kpl + g);
    float4 vv = *reinterpret_cast<const float4*>(vpl + g);
    ushort4 kh = { f2bf(kv.x), f2bf(kv.y), f2bf(kv.z), f2bf(kv.w) };
    ushort4 vh = { f2bf(vv.x), f2bf(vv.y), f2bf(vv.z), f2bf(vv.w) };
    *reinterpret_cast<ushort4*>(&sK[tok * QSTR + c4]) = kh;
    sVt[(c4 + 0) * PSTR + tok] = vh.x;
    sVt[(c4 + 1) * PSTR + tok] = vh.y;
    sVt[(c4 + 2) * PSTR + tok] = vh.z;
    sVt[(c4 + 3) * PSTR + tok] = vh.w;
    if (WSOUT) {
      ushort4 vh16 = { f2h(vv.x), f2h(vv.y), f2h(vv.z), f2h(vv.w) };
      *reinterpret_cast<ushort4*>(wvpl + g) = vh16;   // V fp16 handoff
    }
  }

  const int wv = t >> 6, lane = t & 63;
  const int lr = lane & 15;
  const int lg = lane >> 4;
  const int r0 = (2 * wv) * 16;
  const int r1 = (2 * wv + 1) * 16;

  s16x8 a0 = {0,0,0,0,0,0,0,0}, a1 = {0,0,0,0,0,0,0,0};
  if (lg < 3) {
    union { s16x8 v; ushort u[8]; } qa;
    int tok = r0 + lr;
    const float* qp = qpl + (tok >> 1) * WC + (wq * 2 + (tok & 1)) * 96 + hc + lg * 8;
    float4 x0 = *reinterpret_cast<const float4*>(qp);
    float4 x1 = *reinterpret_cast<const float4*>(qp + 4);
    qa.u[0] = f2bf(x0.x * SCALE); qa.u[1] = f2bf(x0.y * SCALE);
    qa.u[2] = f2bf(x0.z * SCALE); qa.u[3] = f2bf(x0.w * SCALE);
    qa.u[4] = f2bf(x1.x * SCALE); qa.u[5] = f2bf(x1.y * SCALE);
    qa.u[6] = f2bf(x1.z * SCALE); qa.u[7] = f2bf(x1.w * SCALE);
    a0 = qa.v;
    tok = r1 + lr;
    qp = qpl + (tok >> 1) * WC + (wq * 2 + (tok & 1)) * 96 + hc + lg * 8;
    x0 = *reinterpret_cast<const float4*>(qp);
    x1 = *reinterpret_cast<const float4*>(qp + 4);
    qa.u[0] = f2bf(x0.x * SCALE); qa.u[1] = f2bf(x0.y * SCALE);
    qa.u[2] = f2bf(x0.z * SCALE); qa.u[3] = f2bf(x0.w * SCALE);
    qa.u[4] = f2bf(x1.x * SCALE); qa.u[5] = f2bf(x1.y * SCALE);
    qa.u[6] = f2bf(x1.z * SCALE); qa.u[7] = f2bf(x1.w * SCALE);
    a1 = qa.v;
  }

  __syncthreads();

  float rsum[2][4];
  #pragma unroll
  for (int rb = 0; rb < 2; ++rb)
    #pragma unroll
    for (int r = 0; r < 4; ++r) rsum[rb][r] = 0.f;

  f32x4 accO[2][2];
  #pragma unroll
  for (int i = 0; i < 2; ++i)
    #pragma unroll
    for (int j = 0; j < 2; ++j) accO[i][j] = f32x4{0.f, 0.f, 0.f, 0.f};

  #pragma unroll
  for (int half = 0; half < 2; ++half) {
    f32x4 accS[2][4];
    #pragma unroll
    for (int i = 0; i < 2; ++i)
      #pragma unroll
      for (int j = 0; j < 4; ++j) accS[i][j] = f32x4{0.f, 0.f, 0.f, 0.f};

    #pragma unroll
    for (int nb = 0; nb < 4; ++nb) {
      s16x8 bb = *reinterpret_cast<const s16x8*>(
          &sK[(half * 64 + nb * 16 + lr) * QSTR + lg * 8]);
      accS[0][nb] = __builtin_amdgcn_mfma_f32_16x16x32_bf16(a0, bb, accS[0][nb], 0, 0, 0);
      accS[1][nb] = __builtin_amdgcn_mfma_f32_16x16x32_bf16(a1, bb, accS[1][nb], 0, 0, 0);
    }

    #pragma unroll
    for (int rb = 0; rb < 2; ++rb)
      #pragma unroll
      for (int nb = 0; nb < 4; ++nb)
        #pragma unroll
        for (int r = 0; r < 4; ++r) {
          float e = __expf(accS[rb][nb][r]);
          accS[rb][nb][r] = e;
          rsum[rb][r] += e;
        }

    if (half) __syncthreads();

    #pragma unroll
    for (int rb = 0; rb < 2; ++rb)
      #pragma unroll
      for (int nb = 0; nb < 4; ++nb)
        #pragma unroll
        for (int r = 0; r < 4; ++r)
          sP[((2 * wv + rb) * 16 + lg * 4 + r) * PSTR2 + nb * 16 + lr] =
              f2bf(accS[rb][nb][r]);
    __syncthreads();

    #pragma unroll
    for (int kb = 0; kb < 2; ++kb) {
      int kc = half * 64 + kb * 32 + lg * 8;
      s16x8 pa0 = *reinterpret_cast<const s16x8*>(&sP[(r0 + lr) * PSTR2 + kb * 32 + lg * 8]);
      s16x8 pa1 = *reinterpret_cast<const s16x8*>(&sP[(r1 + lr) * PSTR2 + kb * 32 + lg * 8]);
      s16x8 vb0 = *reinterpret_cast<const s16x8*>(&sVt[lr * PSTR + kc]);
      s16x8 vb1 = *reinterpret_cast<const s16x8*>(&sVt[(16 + lr) * PSTR + kc]);
      accO[0][0] = __builtin_amdgcn_mfma_f32_16x16x32_bf16(pa0, vb0, accO[0][0], 0, 0, 0);
      accO[0][1] = __builtin_amdgcn_mfma_f32_16x16x32_bf16(pa0, vb1, accO[0][1], 0, 0, 0);
      accO[1][0] = __builtin_amdgcn_mfma_f32_16x16x32_bf16(pa1, vb0, accO[1][0], 0, 0, 0);
      accO[1][1] = __builtin_amdgcn_mfma_f32_16x16x32_bf16(pa1, vb1, accO[1][1], 0, 0, 0);
    }
  }

  // ---- row-sum reduce ----
  float invs[2][4];
  #pragma unroll
  for (int rb = 0; rb < 2; ++rb) {
    #pragma unroll
    for (int r = 0; r < 4; ++r) {
      float s = rsum[rb][r];
      s += __shfl_xor(s, 1); s += __shfl_xor(s, 2);
      s += __shfl_xor(s, 4); s += __shfl_xor(s, 8);
      invs[rb][r] = 1.0f / s;
    }
  }

  if (WSOUT) {
    // ---- coalesced epilogue: stage bf16 into dead sP [tok][24], then ushort4 ----
    __syncthreads();   // last PV reads of sP done
    #pragma unroll
    for (int rb = 0; rb < 2; ++rb)
      #pragma unroll
      for (int r = 0; r < 4; ++r) {
        int tok = (2 * wv + rb) * 16 + lg * 4 + r;
        float inv = invs[rb][r];
        sP[tok * 24 + lr] = f2bf(accO[rb][0][r] * inv);
        if (lr < 8) sP[tok * 24 + 16 + lr] = f2bf(accO[rb][1][r] * inv);
      }
    __syncthreads();
    ushort* wpl = ws + (size_t)(b * 8 + d) * HWC;
    #pragma unroll
    for (int it = 0; it < 3; ++it) {
      int idx = t + it * 256;                 // 768 ushort4 chunks
      int tok = idx / 6, c4 = (idx - tok * 6) * 4;
      int g = (tok >> 1) * WC + (wq * 2 + (tok & 1)) * 96 + hc + c4;
      *reinterpret_cast<ushort4*>(wpl + g) =
          *reinterpret_cast<const ushort4*>(&sP[tok * 24 + c4]);
    }
  } else {
    float* opl = out + (size_t)(b * 8 + d) * HWC;
    #pragma unroll
    for (int rb = 0; rb < 2; ++rb) {
      #pragma unroll
      for (int r = 0; r < 4; ++r) {
        int tok = (2 * wv + rb) * 16 + lg * 4 + r;
        int g = (tok >> 1) * WC + (wq * 2 + (tok & 1)) * 96 + hc;
        float inv = invs[rb][r];
        opl[g + lr] = accO[rb][0][r] * inv;
        if (lr < 8) opl[g + 16 + lr] = accO[rb][1][r] * inv;
      }
    }
  }
}

// ====== Kernel CB: LePE + MFMA proj — async DMA dbuf + fp16 mix-FMA taps ======
// (unchanged from r22)
constexpr int WSTR = 104;
constexpr int VROW = 96;
constexpr int VBUF = 66 * VROW;

template <bool WSIN>
__global__ void __launch_bounds__(256, 2)
lepe_proj_fused_kernel(const float* __restrict__ qkv, const float* __restrict__ cw,
                       const float* __restrict__ cbias, const float* __restrict__ pw,
                       const float* __restrict__ pb, float* __restrict__ io,
                       const ushort* __restrict__ ws) {
  __shared__ ushort sV2[2][VBUF];     // 25344 B fp16 (rows 0,65 = zero halo)
  __shared__ ushort sW[96 * WSTR];    // 19968 B bf16 proj weight
  __shared__ ushort sCW[27 * 96];     //  5184 B fp16 conv weights [tap][c]
  __shared__ float  sCB[96];
  __shared__ float  sPB[96];

  const int t   = threadIdx.x;
  const int bid = xswz8(blockIdx.x, 1024);
  const int h   = bid & 63;
  const int d   = (bid >> 6) & 7;
  const int b   = bid >> 9;

  const int wvq = t >> 6, lane = t & 63;

  float* iop = io + (size_t)(b * 8 + d) * HWC + h * WC;
  const ushort* wsp = ws + (size_t)(b * 8 + d) * HWC + h * WC;
  const ushort* wvb = ws + BDHWC + (size_t)b * 8 * HWC;
  const float* vbatch = qkv + 2 * (size_t)BDHWC + (size_t)b * 8 * HWC;

  const int tt  = t >> 2;
  const int cbk = (t & 3) * 24;

  float lep[24];
  if (WSIN) {
    union { s16x8 v; ushort u[8]; } azu[3];
    #pragma unroll
    for (int k = 0; k < 3; ++k)
      azu[k].v = *reinterpret_cast<const s16x8*>(wsp + tt * 96 + cbk + k * 8);
    #pragma unroll
    for (int k = 0; k < 3; ++k)
      #pragma unroll
      for (int e = 0; e < 8; ++e) lep[8*k+e] = bf2f(azu[k].u[e]);
  } else {
    float4 az[6];
    #pragma unroll
    for (int j = 0; j < 6; ++j)
      az[j] = *reinterpret_cast<const float4*>(iop + tt * 96 + cbk + j * 4);
    #pragma unroll
    for (int j = 0; j < 6; ++j) {
      lep[4*j+0] = az[j].x; lep[4*j+1] = az[j].y;
      lep[4*j+2] = az[j].z; lep[4*j+3] = az[j].w;
    }
  }

  if (t < 48) {
    const s16x8 Z = {0, 0, 0, 0, 0, 0, 0, 0};
    int buf = t / 24, rr = t - buf * 24;
    int row = (rr < 12) ? 0 : 65;
    int col = (rr < 12 ? rr : rr - 12) * 8;
    *reinterpret_cast<s16x8*>(&sV2[buf][row * VROW + col]) = Z;
  }

  #pragma unroll
  for (int it = 0; it < 9; ++it) {
    int idx = t + it * 256;
    int co = idx / 24, c4 = (idx - co * 24) * 4;
    float4 x = *reinterpret_cast<const float4*>(pw + co * 96 + c4);
    ushort4 hx = { f2bf(x.x), f2bf(x.y), f2bf(x.z), f2bf(x.w) };
    *reinterpret_cast<ushort4*>(&sW[co * WSTR + c4]) = hx;
  }
  for (int idx = t; idx < 2592; idx += 256) {
    int c = idx / 27, tap = idx - c * 27;
    sCW[tap * 96 + c] = f2h(cw[idx]);
  }
  if (t < 96) { sCB[t] = cbias[t]; sPB[t] = pb[t]; }

  int   zdc[3], zhc[3];
  float fdc[3], fhc[3];
  #pragma unroll
  for (int j = 0; j < 3; ++j) {
    int zd = d + j - 1;
    fdc[j] = (zd >= 0 && zd < D_) ? 1.f : 0.f;
    zdc[j] = zd < 0 ? 0 : (zd > D_ - 1 ? D_ - 1 : zd);
    int zh = h + j - 1;
    fhc[j] = (zh >= 0 && zh < H_) ? 1.f : 0.f;
    zhc[j] = zh < 0 ? 0 : (zh > H_ - 1 ? H_ - 1 : zh);
  }

  #define TAP(BI, row, tap)                                                  \
    {                                                                        \
      _Pragma("unroll")                                                      \
      for (int j8 = 0; j8 < 3; ++j8) {                                       \
        union { s16x8 v; __half u[8]; } vu;                                  \
        vu.v = *reinterpret_cast<const s16x8*>(&sV2[BI][(row) * VROW + cbk + j8 * 8]); \
        union { s16x8 v; __half u[8]; } wu;                                  \
        wu.v = *reinterpret_cast<const s16x8*>(&sCW[(tap) * 96 + cbk + j8 * 8]); \
        _Pragma("unroll")                                                    \
        for (int e = 0; e < 8; ++e)                                          \
          lep[8*j8+e] = fmaf(__half2float(vu.u[e]), __half2float(wu.u[e]),   \
                             lep[8*j8+e]);                                   \
      }                                                                      \
    }
  #define DMA(zd, zh, BI)                                                    \
    {                                                                        \
      const ushort* vrow_ = wvb + (size_t)(zd) * HWC + (zh) * WC;            \
      _Pragma("unroll")                                                      \
      for (int c_ = 0; c_ < 3; ++c_) {                                       \
        int ch_ = c_ * 4 + wvq;                                              \
        __builtin_amdgcn_global_load_lds(                                    \
            (const __attribute__((address_space(1))) void*)(vrow_ + ch_ * 512 + lane * 8), \
            (__attribute__((address_space(3))) void*)(&sV2[BI][VROW + ch_ * 512]), \
            16, 0, 0);                                                       \
      }                                                                      \
    }

  if (WSIN) {
    DMA(zdc[0], zhc[0], 0);
    __syncthreads();
    #pragma unroll
    for (int r = 0; r < 9; ++r) {
      const int dd = r / 3, dh = r - 3 * dd;
      if (r < 8) {
        const int nr = r + 1, nd = nr / 3, nh = nr - 3 * nd;
        DMA(zdc[nd], zhc[nh], nr & 1);
      }
      if (fdc[dd] * fhc[dh] != 0.f) {
        TAP(r & 1, tt,     r * 3 + 0);
        TAP(r & 1, tt + 1, r * 3 + 1);
        TAP(r & 1, tt + 2, r * 3 + 2);
      }
      __syncthreads();
    }
  } else {
    #pragma unroll
    for (int dd = 0; dd < 3; ++dd) {
      int zd = d + dd - 1;
      if (zd < 0 || zd >= D_) continue;
      #pragma unroll
      for (int dh = 0; dh < 3; ++dh) {
        int zh = h + dh - 1;
        if (zh < 0 || zh >= H_) continue;
        __syncthreads();
        const float4* src = reinterpret_cast<const float4*>(
            vbatch + (size_t)zd * HWC + zh * WC);
        #pragma unroll
        for (int it = 0; it < 6; ++it) {
          int idx = t + it * 256;
          int tok = idx / 24, c4 = idx - tok * 24;
          float4 x = src[idx];
          ushort4 hx = { f2h(x.x), f2h(x.y), f2h(x.z), f2h(x.w) };
          *reinterpret_cast<ushort4*>(&sV2[0][(tok + 1) * VROW + c4 * 4]) = hx;
        }
        __syncthreads();
        const int tap0 = dd * 9 + dh * 3;
        TAP(0, tt,     tap0 + 0);
        TAP(0, tt + 1, tap0 + 1);
        TAP(0, tt + 2, tap0 + 2);
      }
    }
    __syncthreads();
  }
  #undef TAP
  #undef DMA

  #pragma unroll
  for (int j = 0; j < 6; ++j) {
    float4 bz = *reinterpret_cast<const float4*>(sCB + cbk + j * 4);
    ushort4 hx = { f2bf(lep[4*j+0] + bz.x), f2bf(lep[4*j+1] + bz.y),
                   f2bf(lep[4*j+2] + bz.z), f2bf(lep[4*j+3] + bz.w) };
    *reinterpret_cast<ushort4*>(&sV2[0][tt * 96 + cbk + j * 4]) = hx;
  }
  __syncthreads();

  const int lr = lane & 15, lg = lane >> 4;

  f32x4 acc[6];
  #pragma unroll
  for (int cb = 0; cb < 6; ++cb) {
    float bv = sPB[cb * 16 + lr];
    acc[cb] = f32x4{bv, bv, bv, bv};
  }
  s16x8 afr[3];
  #pragma unroll
  for (int kb = 0; kb < 3; ++kb)
    afr[kb] = *reinterpret_cast<const s16x8*>(&sV2[0][(wvq * 16 + lr) * 96 + kb * 32 + lg * 8]);
  #pragma unroll
  for (int kb = 0; kb < 3; ++kb) {
    #pragma unroll
    for (int cb = 0; cb < 6; ++cb) {
      s16x8 bfr = *reinterpret_cast<const s16x8*>(&sW[(cb * 16 + lr) * WSTR + kb * 32 + lg * 8]);
      acc[cb] = __builtin_amdgcn_mfma_f32_16x16x32_bf16(afr[kb], bfr, acc[cb], 0, 0, 0);
    }
  }

  #pragma unroll
  for (int cb = 0; cb < 6; ++cb) {
    #pragma unroll
    for (int r = 0; r < 4; ++r) {
      int tok = wvq * 16 + lg * 4 + r;
      iop[tok * 96 + cb * 16 + lr] = acc[cb][r];
    }
  }
}

extern "C" void kernel_launch(void* const* d_in, const int* in_sizes, int n_in,
                              void* d_out, int out_size, void* d_ws, size_t ws_size,
                              hipStream_t stream) {
  const float* qkv = (const float*)d_in[0];
  const float* cw  = (const float*)d_in[1];
  const float* cb  = (const float*)d_in[2];
  const float* pw  = (const float*)d_in[3];
  const float* pb  = (const float*)d_in[4];
  float* out = (float*)d_out;
  ushort* ws = (ushort*)d_ws;

  const size_t need = (size_t)2 * BDHWC * sizeof(ushort);  // 25.2 MB
  if (ws_size >= need) {
    hipLaunchKernelGGL((attn_mfma_kernel<true>), dim3(2048), dim3(256), 0, stream,
                       qkv, out, ws);
    hipLaunchKernelGGL((lepe_proj_fused_kernel<true>), dim3(1024), dim3(256), 0, stream,
                       qkv, cw, cb, pw, pb, out, ws);
  } else {
    hipLaunchKernelGGL((attn_mfma_kernel<false>), dim3(2048), dim3(256), 0, stream,
                       qkv, out, ws);
    hipLaunchKernelGGL((lepe_proj_fused_kernel<false>), dim3(1024), dim3(256), 0, stream,
                       qkv, cw, cb, pw, pb, out, ws);
  }
}

// Round 25
// 52.657 us; speedup vs baseline: 1.1796x; 1.0198x over previous
//
#include <hip/hip_runtime.h>
#include <hip/hip_bf16.h>
#include <hip/hip_fp16.h>

constexpr int D_ = 8, H_ = 64, W_ = 64, C_ = 96;
constexpr int WC    = W_ * C_;            // 6144
constexpr int HWC   = H_ * W_ * C_;       // 393216
constexpr int BDHWC = 2 * D_ * HWC;       // 6291456 (elements per tensor)
constexpr float SCALE = 0.10206207261596577f;  // (384/4)^-0.5

typedef __attribute__((ext_vector_type(4))) float f32x4;
typedef __attribute__((ext_vector_type(8))) short s16x8;

__device__ inline ushort f2bf(float x) {
  union { __hip_bfloat16 h; ushort u; } c;
  c.h = __float2bfloat16(x);
  return c.u;
}
__device__ inline float bf2f(ushort u) {
  union { float f; unsigned i; } c;
  c.i = ((unsigned)u) << 16;
  return c.f;
}
__device__ inline ushort f2h(float x) {
  union { __half h; ushort u; } c;
  c.h = __float2half(x);
  return c.u;
}
__device__ inline int xswz8(int bid, int nwg) {
  return (bid & 7) * (nwg >> 3) + (bid >> 3);
}

// ================= Kernel A: MFMA attention, half-P, 37.4KB LDS =================
// (unchanged from r23 — bf16/fp16 ws handoff + coalesced sP epilogue)
constexpr int QSTR  = 40;
constexpr int PSTR  = 136;
constexpr int PSTR2 = 72;

template <bool WSOUT>
__global__ void __launch_bounds__(256, 4)
attn_mfma_kernel(const float* __restrict__ qkv, float* __restrict__ out,
                 ushort* __restrict__ ws) {
  __shared__ ushort sK[128 * QSTR];    // 10240 B
  __shared__ ushort sVt[32 * PSTR];    //  8704 B
  __shared__ ushort sP[128 * PSTR2];   // 18432 B (reused as output stage)

  const int t    = threadIdx.x;
  const int bid  = xswz8(blockIdx.x, 2048);
  const int head = bid & 3;
  const int nw   = bid >> 2;
  const int wq   = nw & 31;
  const int d    = (nw >> 5) & 7;
  const int b    = nw >> 8;
  const int hc   = head * 24;

  const float* qpl = qkv + (size_t)(b * 8 + d) * HWC;
  const float* kpl = qpl + BDHWC;
  const float* vpl = kpl + BDHWC;
  ushort* wvpl = ws + BDHWC + (size_t)(b * 8 + d) * HWC;   // V fp16 out

  {
    const s16x8 Z = {0, 0, 0, 0, 0, 0, 0, 0};
    int row = t >> 1, col = 24 + (t & 1) * 8;
    *reinterpret_cast<s16x8*>(&sK[row * QSTR + col]) = Z;
    if (t < 136) *reinterpret_cast<s16x8*>(&sVt[24 * PSTR + t * 8]) = Z;
  }

  #pragma unroll
  for (int it = 0; it < 3; ++it) {
    int idx = t + it * 256;
    int tok = idx / 6, c4 = (idx - tok * 6) * 4;
    int g = (tok >> 1) * WC + (wq * 2 + (tok & 1)) * 96 + hc + c4;
    float4 kv = *reinterpret_cast<const float4*>(kpl + g);
    float4 vv = *reinterpret_cast<const float4*>(vpl + g);
    ushort4 kh = { f2bf(kv.x), f2bf(kv.y), f2bf(kv.z), f2bf(kv.w) };
    ushort4 vh = { f2bf(vv.x), f2bf(vv.y), f2bf(vv.z), f2bf(vv.w) };
    *reinterpret_cast<ushort4*>(&sK[tok * QSTR + c4]) = kh;
    sVt[(c4 + 0) * PSTR + tok] = vh.x;
    sVt[(c4 + 1) * PSTR + tok] = vh.y;
    sVt[(c4 + 2) * PSTR + tok] = vh.z;
    sVt[(c4 + 3) * PSTR + tok] = vh.w;
    if (WSOUT) {
      ushort4 vh16 = { f2h(vv.x), f2h(vv.y), f2h(vv.z), f2h(vv.w) };
      *reinterpret_cast<ushort4*>(wvpl + g) = vh16;   // V fp16 handoff
    }
  }

  const int wv = t >> 6, lane = t & 63;
  const int lr = lane & 15;
  const int lg = lane >> 4;
  const int r0 = (2 * wv) * 16;
  const int r1 = (2 * wv + 1) * 16;

  s16x8 a0 = {0,0,0,0,0,0,0,0}, a1 = {0,0,0,0,0,0,0,0};
  if (lg < 3) {
    union { s16x8 v; ushort u[8]; } qa;
    int tok = r0 + lr;
    const float* qp = qpl + (tok >> 1) * WC + (wq * 2 + (tok & 1)) * 96 + hc + lg * 8;
    float4 x0 = *reinterpret_cast<const float4*>(qp);
    float4 x1 = *reinterpret_cast<const float4*>(qp + 4);
    qa.u[0] = f2bf(x0.x * SCALE); qa.u[1] = f2bf(x0.y * SCALE);
    qa.u[2] = f2bf(x0.z * SCALE); qa.u[3] = f2bf(x0.w * SCALE);
    qa.u[4] = f2bf(x1.x * SCALE); qa.u[5] = f2bf(x1.y * SCALE);
    qa.u[6] = f2bf(x1.z * SCALE); qa.u[7] = f2bf(x1.w * SCALE);
    a0 = qa.v;
    tok = r1 + lr;
    qp = qpl + (tok >> 1) * WC + (wq * 2 + (tok & 1)) * 96 + hc + lg * 8;
    x0 = *reinterpret_cast<const float4*>(qp);
    x1 = *reinterpret_cast<const float4*>(qp + 4);
    qa.u[0] = f2bf(x0.x * SCALE); qa.u[1] = f2bf(x0.y * SCALE);
    qa.u[2] = f2bf(x0.z * SCALE); qa.u[3] = f2bf(x0.w * SCALE);
    qa.u[4] = f2bf(x1.x * SCALE); qa.u[5] = f2bf(x1.y * SCALE);
    qa.u[6] = f2bf(x1.z * SCALE); qa.u[7] = f2bf(x1.w * SCALE);
    a1 = qa.v;
  }

  __syncthreads();

  float rsum[2][4];
  #pragma unroll
  for (int rb = 0; rb < 2; ++rb)
    #pragma unroll
    for (int r = 0; r < 4; ++r) rsum[rb][r] = 0.f;

  f32x4 accO[2][2];
  #pragma unroll
  for (int i = 0; i < 2; ++i)
    #pragma unroll
    for (int j = 0; j < 2; ++j) accO[i][j] = f32x4{0.f, 0.f, 0.f, 0.f};

  #pragma unroll
  for (int half = 0; half < 2; ++half) {
    f32x4 accS[2][4];
    #pragma unroll
    for (int i = 0; i < 2; ++i)
      #pragma unroll
      for (int j = 0; j < 4; ++j) accS[i][j] = f32x4{0.f, 0.f, 0.f, 0.f};

    #pragma unroll
    for (int nb = 0; nb < 4; ++nb) {
      s16x8 bb = *reinterpret_cast<const s16x8*>(
          &sK[(half * 64 + nb * 16 + lr) * QSTR + lg * 8]);
      accS[0][nb] = __builtin_amdgcn_mfma_f32_16x16x32_bf16(a0, bb, accS[0][nb], 0, 0, 0);
      accS[1][nb] = __builtin_amdgcn_mfma_f32_16x16x32_bf16(a1, bb, accS[1][nb], 0, 0, 0);
    }

    #pragma unroll
    for (int rb = 0; rb < 2; ++rb)
      #pragma unroll
      for (int nb = 0; nb < 4; ++nb)
        #pragma unroll
        for (int r = 0; r < 4; ++r) {
          float e = __expf(accS[rb][nb][r]);
          accS[rb][nb][r] = e;
          rsum[rb][r] += e;
        }

    if (half) __syncthreads();

    #pragma unroll
    for (int rb = 0; rb < 2; ++rb)
      #pragma unroll
      for (int nb = 0; nb < 4; ++nb)
        #pragma unroll
        for (int r = 0; r < 4; ++r)
          sP[((2 * wv + rb) * 16 + lg * 4 + r) * PSTR2 + nb * 16 + lr] =
              f2bf(accS[rb][nb][r]);
    __syncthreads();

    #pragma unroll
    for (int kb = 0; kb < 2; ++kb) {
      int kc = half * 64 + kb * 32 + lg * 8;
      s16x8 pa0 = *reinterpret_cast<const s16x8*>(&sP[(r0 + lr) * PSTR2 + kb * 32 + lg * 8]);
      s16x8 pa1 = *reinterpret_cast<const s16x8*>(&sP[(r1 + lr) * PSTR2 + kb * 32 + lg * 8]);
      s16x8 vb0 = *reinterpret_cast<const s16x8*>(&sVt[lr * PSTR + kc]);
      s16x8 vb1 = *reinterpret_cast<const s16x8*>(&sVt[(16 + lr) * PSTR + kc]);
      accO[0][0] = __builtin_amdgcn_mfma_f32_16x16x32_bf16(pa0, vb0, accO[0][0], 0, 0, 0);
      accO[0][1] = __builtin_amdgcn_mfma_f32_16x16x32_bf16(pa0, vb1, accO[0][1], 0, 0, 0);
      accO[1][0] = __builtin_amdgcn_mfma_f32_16x16x32_bf16(pa1, vb0, accO[1][0], 0, 0, 0);
      accO[1][1] = __builtin_amdgcn_mfma_f32_16x16x32_bf16(pa1, vb1, accO[1][1], 0, 0, 0);
    }
  }

  float invs[2][4];
  #pragma unroll
  for (int rb = 0; rb < 2; ++rb) {
    #pragma unroll
    for (int r = 0; r < 4; ++r) {
      float s = rsum[rb][r];
      s += __shfl_xor(s, 1); s += __shfl_xor(s, 2);
      s += __shfl_xor(s, 4); s += __shfl_xor(s, 8);
      invs[rb][r] = 1.0f / s;
    }
  }

  if (WSOUT) {
    __syncthreads();
    #pragma unroll
    for (int rb = 0; rb < 2; ++rb)
      #pragma unroll
      for (int r = 0; r < 4; ++r) {
        int tok = (2 * wv + rb) * 16 + lg * 4 + r;
        float inv = invs[rb][r];
        sP[tok * 24 + lr] = f2bf(accO[rb][0][r] * inv);
        if (lr < 8) sP[tok * 24 + 16 + lr] = f2bf(accO[rb][1][r] * inv);
      }
    __syncthreads();
    ushort* wpl = ws + (size_t)(b * 8 + d) * HWC;
    #pragma unroll
    for (int it = 0; it < 3; ++it) {
      int idx = t + it * 256;
      int tok = idx / 6, c4 = (idx - tok * 6) * 4;
      int g = (tok >> 1) * WC + (wq * 2 + (tok & 1)) * 96 + hc + c4;
      *reinterpret_cast<ushort4*>(wpl + g) =
          *reinterpret_cast<const ushort4*>(&sP[tok * 24 + c4]);
    }
  } else {
    float* opl = out + (size_t)(b * 8 + d) * HWC;
    #pragma unroll
    for (int rb = 0; rb < 2; ++rb) {
      #pragma unroll
      for (int r = 0; r < 4; ++r) {
        int tok = (2 * wv + rb) * 16 + lg * 4 + r;
        int g = (tok >> 1) * WC + (wq * 2 + (tok & 1)) * 96 + hc;
        float inv = invs[rb][r];
        opl[g + lr] = accO[rb][0][r] * inv;
        if (lr < 8) opl[g + 16 + lr] = accO[rb][1][r] * inv;
      }
    }
  }
}

// ====== Kernel CB: LePE + proj — DMA dbuf + mix-FMA + phase-disjoint LDS ======
// sMem union: taps = {buf0[6336], buf1[6336], sCW[2592]}; proj = {sA = buf0,
// sW over buf1+sCW}. Total 33.4KB -> 4 blocks/CU (if VGPR<=128). sW staged
// AFTER taps (pw is L2-hot across 1024 blocks). Taps/DMA CFG identical to r22.
constexpr int WSTR   = 104;
constexpr int VROW   = 96;
constexpr int VBUFU  = 66 * VROW;       // 6336 ushorts per V buffer
constexpr int SMEM_U = 2 * VBUFU + 96 * WSTR - VBUFU;  // 16320 (buf0+max(buf1+sCW, sW))

template <bool WSIN>
__global__ void __launch_bounds__(256, 2)
lepe_proj_fused_kernel(const float* __restrict__ qkv, const float* __restrict__ cw,
                       const float* __restrict__ cbias, const float* __restrict__ pw,
                       const float* __restrict__ pb, float* __restrict__ io,
                       const ushort* __restrict__ ws) {
  __shared__ ushort sMem[16320];      // 32640 B union
  __shared__ float  sCB[96];
  __shared__ float  sPB[96];

  ushort* buf0 = sMem;                // taps: V buffer 0 (rows 0,65 = halo)
  ushort* buf1 = sMem + VBUFU;        // taps: V buffer 1
  ushort* sCW  = sMem + 2 * VBUFU;    // taps: fp16 conv weights [tap][c] (2592)
  ushort* sA   = sMem;                // proj: repacked input (6144)
  ushort* sW   = sMem + VBUFU;        // proj: bf16 proj weight (9984)

  const int t   = threadIdx.x;
  const int bid = xswz8(blockIdx.x, 1024);
  const int h   = bid & 63;
  const int d   = (bid >> 6) & 7;
  const int b   = bid >> 9;

  const int wvq = t >> 6, lane = t & 63;

  float* iop = io + (size_t)(b * 8 + d) * HWC + h * WC;
  const ushort* wsp = ws + (size_t)(b * 8 + d) * HWC + h * WC;
  const ushort* wvb = ws + BDHWC + (size_t)b * 8 * HWC;
  const float* vbatch = qkv + 2 * (size_t)BDHWC + (size_t)b * 8 * HWC;

  const int tt  = t >> 2;
  const int cbk = (t & 3) * 24;

  // ---- attn rows: issue reads first ----
  float lep[24];
  if (WSIN) {
    union { s16x8 v; ushort u[8]; } azu[3];
    #pragma unroll
    for (int k = 0; k < 3; ++k)
      azu[k].v = *reinterpret_cast<const s16x8*>(wsp + tt * 96 + cbk + k * 8);
    #pragma unroll
    for (int k = 0; k < 3; ++k)
      #pragma unroll
      for (int e = 0; e < 8; ++e) lep[8*k+e] = bf2f(azu[k].u[e]);
  } else {
    float4 az[6];
    #pragma unroll
    for (int j = 0; j < 6; ++j)
      az[j] = *reinterpret_cast<const float4*>(iop + tt * 96 + cbk + j * 4);
    #pragma unroll
    for (int j = 0; j < 6; ++j) {
      lep[4*j+0] = az[j].x; lep[4*j+1] = az[j].y;
      lep[4*j+2] = az[j].z; lep[4*j+3] = az[j].w;
    }
  }

  // ---- zero halo rows (rows 0,65 of both buffers), once ----
  if (t < 48) {
    const s16x8 Z = {0, 0, 0, 0, 0, 0, 0, 0};
    ushort* bp = (t < 24) ? buf0 : buf1;
    int rr = (t < 24) ? t : t - 24;
    int row = (rr < 12) ? 0 : 65;
    int col = (rr < 12 ? rr : rr - 12) * 8;
    *reinterpret_cast<s16x8*>(&bp[row * VROW + col]) = Z;
  }

  // ---- conv weights fp16 + biases (sW staged later, post-taps) ----
  for (int idx = t; idx < 2592; idx += 256) {
    int c = idx / 27, tap = idx - c * 27;
    sCW[tap * 96 + c] = f2h(cw[idx]);
  }
  if (t < 96) { sCB[t] = cbias[t]; sPB[t] = pb[t]; }

  // ---- clamped region coords & validity (block-uniform) ----
  int   zdc[3], zhc[3];
  float fdc[3], fhc[3];
  #pragma unroll
  for (int j = 0; j < 3; ++j) {
    int zd = d + j - 1;
    fdc[j] = (zd >= 0 && zd < D_) ? 1.f : 0.f;
    zdc[j] = zd < 0 ? 0 : (zd > D_ - 1 ? D_ - 1 : zd);
    int zh = h + j - 1;
    fhc[j] = (zh >= 0 && zh < H_) ? 1.f : 0.f;
    zhc[j] = zh < 0 ? 0 : (zh > H_ - 1 ? H_ - 1 : zh);
  }

  #define TAP(BP, row, tap)                                                  \
    {                                                                        \
      _Pragma("unroll")                                                      \
      for (int j8 = 0; j8 < 3; ++j8) {                                       \
        union { s16x8 v; __half u[8]; } vu;                                  \
        vu.v = *reinterpret_cast<const s16x8*>(&(BP)[(row) * VROW + cbk + j8 * 8]); \
        union { s16x8 v; __half u[8]; } wu;                                  \
        wu.v = *reinterpret_cast<const s16x8*>(&sCW[(tap) * 96 + cbk + j8 * 8]); \
        _Pragma("unroll")                                                    \
        for (int e = 0; e < 8; ++e)                                          \
          lep[8*j8+e] = fmaf(__half2float(vu.u[e]), __half2float(wu.u[e]),   \
                             lep[8*j8+e]);                                   \
      }                                                                      \
    }
  #define DMA(zd, zh, BP)                                                    \
    {                                                                        \
      const ushort* vrow_ = wvb + (size_t)(zd) * HWC + (zh) * WC;            \
      _Pragma("unroll")                                                      \
      for (int c_ = 0; c_ < 3; ++c_) {                                       \
        int ch_ = c_ * 4 + wvq;                                              \
        __builtin_amdgcn_global_load_lds(                                    \
            (const __attribute__((address_space(1))) void*)(vrow_ + ch_ * 512 + lane * 8), \
            (__attribute__((address_space(3))) void*)(&(BP)[VROW + ch_ * 512]), \
            16, 0, 0);                                                       \
      }                                                                      \
    }

  if (WSIN) {
    DMA(zdc[0], zhc[0], buf0);
    __syncthreads();
    #pragma unroll
    for (int r = 0; r < 9; ++r) {
      const int dd = r / 3, dh = r - 3 * dd;
      if (r < 8) {
        const int nr = r + 1, nd = nr / 3, nh = nr - 3 * nd;
        DMA(zdc[nd], zhc[nh], ((nr & 1) ? buf1 : buf0));
      }
      if (fdc[dd] * fhc[dh] != 0.f) {
        ushort* bp = (r & 1) ? buf1 : buf0;
        TAP(bp, tt,     r * 3 + 0);
        TAP(bp, tt + 1, r * 3 + 1);
        TAP(bp, tt + 2, r * 3 + 2);
      }
      __syncthreads();
    }
  } else {
    #pragma unroll
    for (int dd = 0; dd < 3; ++dd) {
      int zd = d + dd - 1;
      if (zd < 0 || zd >= D_) continue;
      #pragma unroll
      for (int dh = 0; dh < 3; ++dh) {
        int zh = h + dh - 1;
        if (zh < 0 || zh >= H_) continue;
        __syncthreads();
        const float4* src = reinterpret_cast<const float4*>(
            vbatch + (size_t)zd * HWC + zh * WC);
        #pragma unroll
        for (int it = 0; it < 6; ++it) {
          int idx = t + it * 256;
          int tok = idx / 24, c4 = idx - tok * 24;
          float4 x = src[idx];
          ushort4 hx = { f2h(x.x), f2h(x.y), f2h(x.z), f2h(x.w) };
          *reinterpret_cast<ushort4*>(&buf0[(tok + 1) * VROW + c4 * 4]) = hx;
        }
        __syncthreads();
        const int tap0 = dd * 9 + dh * 3;
        TAP(buf0, tt,     tap0 + 0);
        TAP(buf0, tt + 1, tap0 + 1);
        TAP(buf0, tt + 2, tap0 + 2);
      }
    }
    __syncthreads();
  }
  #undef TAP
  #undef DMA

  // ---- proj phase: stage sW (buf1+sCW dead) + repack into sA (buf0 dead) ----
  #pragma unroll
  for (int it = 0; it < 9; ++it) {
    int idx = t + it * 256;
    int co = idx / 24, c4 = (idx - co * 24) * 4;
    float4 x = *reinterpret_cast<const float4*>(pw + co * 96 + c4);
    ushort4 hx = { f2bf(x.x), f2bf(x.y), f2bf(x.z), f2bf(x.w) };
    *reinterpret_cast<ushort4*>(&sW[co * WSTR + c4]) = hx;
  }
  #pragma unroll
  for (int j = 0; j < 6; ++j) {
    float4 bz = *reinterpret_cast<const float4*>(sCB + cbk + j * 4);
    ushort4 hx = { f2bf(lep[4*j+0] + bz.x), f2bf(lep[4*j+1] + bz.y),
                   f2bf(lep[4*j+2] + bz.z), f2bf(lep[4*j+3] + bz.w) };
    *reinterpret_cast<ushort4*>(&sA[tt * 96 + cbk + j * 4]) = hx;
  }
  __syncthreads();

  const int lr = lane & 15, lg = lane >> 4;

  f32x4 acc[6];
  #pragma unroll
  for (int cb = 0; cb < 6; ++cb) {
    float bv = sPB[cb * 16 + lr];
    acc[cb] = f32x4{bv, bv, bv, bv};
  }
  s16x8 afr[3];
  #pragma unroll
  for (int kb = 0; kb < 3; ++kb)
    afr[kb] = *reinterpret_cast<const s16x8*>(&sA[(wvq * 16 + lr) * 96 + kb * 32 + lg * 8]);
  #pragma unroll
  for (int kb = 0; kb < 3; ++kb) {
    #pragma unroll
    for (int cb = 0; cb < 6; ++cb) {
      s16x8 bfr = *reinterpret_cast<const s16x8*>(&sW[(cb * 16 + lr) * WSTR + kb * 32 + lg * 8]);
      acc[cb] = __builtin_amdgcn_mfma_f32_16x16x32_bf16(afr[kb], bfr, acc[cb], 0, 0, 0);
    }
  }

  #pragma unroll
  for (int cb = 0; cb < 6; ++cb) {
    #pragma unroll
    for (int r = 0; r < 4; ++r) {
      int tok = wvq * 16 + lg * 4 + r;
      iop[tok * 96 + cb * 16 + lr] = acc[cb][r];
    }
  }
}

extern "C" void kernel_launch(void* const* d_in, const int* in_sizes, int n_in,
                              void* d_out, int out_size, void* d_ws, size_t ws_size,
                              hipStream_t stream) {
  const float* qkv = (const float*)d_in[0];
  const float* cw  = (const float*)d_in[1];
  const float* cb  = (const float*)d_in[2];
  const float* pw  = (const float*)d_in[3];
  const float* pb  = (const float*)d_in[4];
  float* out = (float*)d_out;
  ushort* ws = (ushort*)d_ws;

  const size_t need = (size_t)2 * BDHWC * sizeof(ushort);  // 25.2 MB
  if (ws_size >= need) {
    hipLaunchKernelGGL((attn_mfma_kernel<true>), dim3(2048), dim3(256), 0, stream,
                       qkv, out, ws);
    hipLaunchKernelGGL((lepe_proj_fused_kernel<true>), dim3(1024), dim3(256), 0, stream,
                       qkv, cw, cb, pw, pb, out, ws);
  } else {
    hipLaunchKernelGGL((attn_mfma_kernel<false>), dim3(2048), dim3(256), 0, stream,
                       qkv, out, ws);
    hipLaunchKernelGGL((lepe_proj_fused_kernel<false>), dim3(1024), dim3(256), 0, stream,
                       qkv, cw, cb, pw, pb, out, ws);
  }
}